// Round 5
// baseline (1060.975 us; speedup 1.0000x reference)
//
#include <hip/hip_runtime.h>
#include <cstdint>
#include <cstddef>

#define IMG 512
#define JD 192

__device__ inline float fast_rcp(float x) { return __builtin_amdgcn_rcpf(x); }
// intra-wave LDS store->load ordering fence (no cross-wave sync needed when a
// single wave owns the data): waits out DS queue + stops compiler reordering.
__device__ inline void lds_fence() {
  asm volatile("s_waitcnt lgkmcnt(0)" ::: "memory");
}

// ---------------------------------------------------------------------------
// K1: partial Gram. grid (4 patch-chunks, 4 row-slabs, 16 batches), 256 thr.
// ---------------------------------------------------------------------------
__global__ __launch_bounds__(256) void k_gram(const float* __restrict__ x,
                                              float* __restrict__ part) {
  const int ck = blockIdx.x;
  const int sl = blockIdx.y;
  const int b  = blockIdx.z;
  const int t  = threadIdx.x;
  __shared__ float tile[32][JD];
  const int ty = t >> 5;
  const int tx = t & 31;
  const int r0 = sl*48 + ty*6;
  const int c0 = tx*6;
  float acc[6][6];
#pragma unroll
  for (int i=0;i<6;i++)
#pragma unroll
    for (int j=0;j<6;j++) acc[i][j]=0.f;
  const float* xb = x + (size_t)b*3*IMG*IMG;
  const int nbeg = ck*1024;
  for (int n0 = nbeg; n0 < nbeg+1024; n0 += 32) {
    for (int f = t; f < 32*JD; f += 256) {
      const int nl = f / JD, j = f - nl*JD;
      const int n = n0 + nl;
      const int hh = n >> 6, ww = n & 63;
      const int c = j >> 6, p = (j >> 3) & 7, q = j & 7;
      tile[nl][j] = xb[(c*IMG + hh*8+p)*IMG + ww*8 + q];
    }
    __syncthreads();
#pragma unroll 4
    for (int nl = 0; nl < 32; nl++) {
      float va[6], vb[6];
#pragma unroll
      for (int i=0;i<6;i++) va[i] = tile[nl][r0+i];
#pragma unroll
      for (int j=0;j<6;j++) vb[j] = tile[nl][c0+j];
#pragma unroll
      for (int i=0;i<6;i++)
#pragma unroll
        for (int j=0;j<6;j++) acc[i][j] += va[i]*vb[j];
    }
    __syncthreads();
  }
  float* dst = part + (((size_t)(b*4 + sl))*4 + ck) * (size_t)(48*JD);
#pragma unroll
  for (int i=0;i<6;i++)
#pragma unroll
    for (int j=0;j<6;j++)
      dst[(ty*6+i)*JD + c0+j] = acc[i][j];
}

// ---------------------------------------------------------------------------
// K2: reduce 4 chunk-partials -> Gs = G / 4096
// ---------------------------------------------------------------------------
__global__ __launch_bounds__(256) void k_greduce(const float* __restrict__ part,
                                                 float* __restrict__ Gs) {
  const int idx = blockIdx.x*256 + threadIdx.x;
  const int b = idx / (JD*JD);
  const int e = idx - b*(JD*JD);
  const int r = e / JD;
  const int sl = r / 48;
  const int w = (r - sl*48)*JD + (e - r*JD);
  const float* p = part + ((size_t)(b*4+sl))*4*(48*JD) + w;
  float s = 0.f;
#pragma unroll
  for (int ck=0; ck<4; ck++) s += p[(size_t)ck*48*JD];
  Gs[idx] = s * (1.0f/4096.0f);
}

// ---------------------------------------------------------------------------
// K3: D = S*S for symmetric S (per batch), lower-tri tile pairs.
// ---------------------------------------------------------------------------
__global__ __launch_bounds__(256) void k_sq(const float* __restrict__ S,
                                            float* __restrict__ D) {
  const int tp = blockIdx.x;
  const int b  = blockIdx.y;
  int ti, tj;
  if      (tp==0){ti=0;tj=0;} else if (tp==1){ti=1;tj=0;}
  else if (tp==2){ti=1;tj=1;} else if (tp==3){ti=2;tj=0;}
  else if (tp==4){ti=2;tj=1;} else            {ti=2;tj=2;}
  const float* Sb = S + (size_t)b*JD*JD;
  float* Db = D + (size_t)b*JD*JD;
  __shared__ float Ar[64][33];
  __shared__ float Br[64][33];
  const int t = threadIdx.x;
  const int ty = t >> 4, tx = t & 15;
  float acc[4][4];
#pragma unroll
  for (int i=0;i<4;i++)
#pragma unroll
    for (int j=0;j<4;j++) acc[i][j]=0.f;
  for (int k0=0; k0<JD; k0+=32) {
    for (int f=t; f<2048; f+=256) {
      const int row = f >> 5, kk = f & 31;
      Ar[row][kk] = Sb[(ti*64+row)*JD + k0+kk];
      Br[row][kk] = Sb[(tj*64+row)*JD + k0+kk];
    }
    __syncthreads();
#pragma unroll 4
    for (int k=0;k<32;k++) {
      float va[4], vb[4];
#pragma unroll
      for (int i=0;i<4;i++) va[i] = Ar[ty*4+i][k];
#pragma unroll
      for (int j=0;j<4;j++) vb[j] = Br[tx*4+j][k];
#pragma unroll
      for (int i=0;i<4;i++)
#pragma unroll
        for (int j=0;j<4;j++) acc[i][j] += va[i]*vb[j];
    }
    __syncthreads();
  }
#pragma unroll
  for (int i=0;i<4;i++)
#pragma unroll
    for (int j=0;j<4;j++) {
      const int r = ti*64+ty*4+i, c = tj*64+tx*4+j;
      Db[r*JD+c] = acc[i][j];
      if (ti != tj) Db[c*JD+r] = acc[i][j];
    }
}

// ---------------------------------------------------------------------------
// LDS-resident helpers (256 threads). W buffers: 192 rows, stride 68 floats.
// ---------------------------------------------------------------------------

// In-place ridge-CholQR of Wl (192x68 LDS). S1 is 64x68 LDS scratch.
__device__ void orth_lds(float* __restrict__ Wl, float* __restrict__ S1,
                         float* __restrict__ rdv, float* __restrict__ pdv,
                         float* __restrict__ misc, int t, float ridge) {
  const int ty = t >> 4, tx = t & 15;
  float acc[4][4];
#pragma unroll
  for (int i=0;i<4;i++)
#pragma unroll
    for (int j=0;j<4;j++) acc[i][j]=0.f;
  __syncthreads();
  // ---- Gram: S1 = W^T W ----
#pragma unroll 2
  for (int r=0; r<JD; r++) {
    const float4 va4 = *(const float4*)(Wl + r*68 + ty*4);
    const float4 vb4 = *(const float4*)(Wl + r*68 + tx*4);
    const float a4[4] = {va4.x, va4.y, va4.z, va4.w};
    const float b4[4] = {vb4.x, vb4.y, vb4.z, vb4.w};
#pragma unroll
    for (int i=0;i<4;i++)
#pragma unroll
      for (int j=0;j<4;j++) acc[i][j] += a4[i]*b4[j];
  }
#pragma unroll
  for (int i=0;i<4;i++)
#pragma unroll
    for (int j=0;j<4;j++)
      S1[(ty*4+i)*68 + tx*4+j] = acc[i][j];
  __syncthreads();
  // ---- ridge ----
  if (ridge > 0.f) {
    if (t < 64) {
      float d = S1[t*68+t];
#pragma unroll
      for (int o=1;o<64;o<<=1) d = fmaxf(d, __shfl_xor(d, o));
      if (t == 0) misc[0] = d * ridge;
    }
    __syncthreads();
    if (t < 64) S1[t*68+t] += misc[0];
    __syncthreads();
  }
  // ---- blocked Cholesky (LDL-form, panel = 16) ----
  for (int p=0; p<4; p++) {
    const int b16 = p*16;
    // phase A: diagonal 16x16 factor, single wave, no barriers
    if (t < 64) {
      for (int jj=0; jj<16; jj++) {
        const int j = b16 + jj;
        const float invd = fast_rcp(S1[j*68+j]);
        if (t == 0) pdv[jj] = invd;
        const int nit = (15-jj)*16;
        for (int f=t; f<nit; f+=64) {
          const int i = j+1 + (f>>4);
          const int k = j+1 + (f&15);
          if (k <= i)
            S1[i*68+k] -= S1[i*68+j]*S1[k*68+j]*invd;
        }
      }
    }
    __syncthreads();
    // phase B: panel rows below diag block, one thread per row (registers)
    const int rb = b16 + 16;
    if (t < 64 - rb) {
      const int r = rb + t;
      float pr[16];
      float4* prp = (float4*)pr;
      prp[0] = *(const float4*)(S1 + r*68 + b16);
      prp[1] = *(const float4*)(S1 + r*68 + b16 + 4);
      prp[2] = *(const float4*)(S1 + r*68 + b16 + 8);
      prp[3] = *(const float4*)(S1 + r*68 + b16 + 12);
#pragma unroll
      for (int c=1; c<16; c++) {
        float s = pr[c];
#pragma unroll
        for (int j=0; j<c; j++) s -= pr[j]*S1[(b16+c)*68 + b16+j]*pdv[j];
        pr[c] = s;
      }
      *(float4*)(S1 + r*68 + b16)      = prp[0];
      *(float4*)(S1 + r*68 + b16 + 4)  = prp[1];
      *(float4*)(S1 + r*68 + b16 + 8)  = prp[2];
      *(float4*)(S1 + r*68 + b16 + 12) = prp[3];
    }
    __syncthreads();
    // phase C: trailing rank-16 update, fully parallel
    for (int f=t; f<2304; f+=256) {
      const int i = rb + f/48;
      const int k = rb + (f - (f/48)*48);
      if (i < 64 && k < 64 && k <= i) {
        float s = S1[i*68+k];
#pragma unroll
        for (int jj=0; jj<16; jj++)
          s -= S1[i*68 + b16+jj]*S1[k*68 + b16+jj]*pdv[jj];
        S1[i*68+k] = s;
      }
    }
    __syncthreads();
  }
  // ---- scale columns, triangular solve in registers ----
  if (t < 64) rdv[t] = rsqrtf(S1[t*68+t]);
  __syncthreads();
  for (int f=t; f<4096; f+=256) {
    const int i = f>>6, k = f&63;
    if (k < i) S1[i*68+k] *= rdv[k];
  }
  __syncthreads();
  if (t < JD) {
    float w[64];
    float4* wp = (float4*)w;
#pragma unroll
    for (int c4=0;c4<16;c4++) wp[c4] = *(const float4*)(Wl + t*68 + c4*4);
#pragma unroll
    for (int c=0;c<64;c++) {
      float v = w[c];
#pragma unroll
      for (int k=0;k<c;k++) v -= w[k]*S1[c*68+k];
      w[c] = v * rdv[c];
    }
#pragma unroll
    for (int c4=0;c4<16;c4++) *(float4*)(Wl + t*68 + c4*4) = wp[c4];
  }
  __syncthreads();
}

// Wout(192x68 LDS) = G(192x192 global) * Win(192x68 LDS); Gt 32x193 scratch
__device__ void mm_lds(const float* __restrict__ G, const float* __restrict__ Win,
                       float* __restrict__ Wout, float* __restrict__ Gt, int t) {
  const int rg = t >> 2, cg = t & 3;
  float acc[3][16];
#pragma unroll
  for (int i=0;i<3;i++)
#pragma unroll
    for (int j=0;j<16;j++) acc[i][j]=0.f;
  for (int k0=0; k0<JD; k0+=32) {
    __syncthreads();
    for (int f=t; f<6144; f+=256) {
      const int r = f >> 5, kk = f & 31;
      Gt[kk*193 + r] = G[r*JD + k0 + kk];
    }
    __syncthreads();
#pragma unroll 2
    for (int k=0;k<32;k++) {
      const float a0 = Gt[k*193 + rg*3+0];
      const float a1 = Gt[k*193 + rg*3+1];
      const float a2 = Gt[k*193 + rg*3+2];
      const float* wr = Win + (k0+k)*68 + cg*16;
#pragma unroll
      for (int j4=0;j4<4;j4++) {
        const float4 b4 = *(const float4*)(wr + 4*j4);
        const float bb[4] = {b4.x, b4.y, b4.z, b4.w};
#pragma unroll
        for (int jj=0;jj<4;jj++) {
          acc[0][j4*4+jj] += a0*bb[jj];
          acc[1][j4*4+jj] += a1*bb[jj];
          acc[2][j4*4+jj] += a2*bb[jj];
        }
      }
    }
  }
  __syncthreads();
#pragma unroll
  for (int i=0;i<3;i++)
#pragma unroll
    for (int j=0;j<16;j++)
      Wout[(rg*3+i)*68 + cg*16 + j] = acc[i][j];
  __syncthreads();
}

// S1 = X^T * Y (both 192x68 LDS), dst stride ss (scalar stores)
__device__ void hgemm_lds(const float* __restrict__ X, const float* __restrict__ Y,
                          float* __restrict__ S1, int ss, int t) {
  const int ty = t >> 4, tx = t & 15;
  float acc[4][4];
#pragma unroll
  for (int i=0;i<4;i++)
#pragma unroll
    for (int j=0;j<4;j++) acc[i][j]=0.f;
#pragma unroll 2
  for (int r=0; r<JD; r++) {
    const float4 va4 = *(const float4*)(X + r*68 + ty*4);
    const float4 vb4 = *(const float4*)(Y + r*68 + tx*4);
    const float a4[4] = {va4.x, va4.y, va4.z, va4.w};
    const float b4[4] = {vb4.x, vb4.y, vb4.z, vb4.w};
#pragma unroll
    for (int i=0;i<4;i++)
#pragma unroll
      for (int j=0;j<4;j++) acc[i][j] += a4[i]*b4[j];
  }
  __syncthreads();
#pragma unroll
  for (int i=0;i<4;i++)
#pragma unroll
    for (int j=0;j<4;j++)
      S1[(ty*4+i)*ss + tx*4+j] = acc[i][j];
  __syncthreads();
}

// Sturm count with fast reciprocal
__device__ inline int sturm_cnt_fast(const float* a, const float* b2, float sig) {
  float d = a[0] - sig;
  int n = (d < 0.f) ? 1 : 0;
#pragma unroll 8
  for (int i=1;i<64;i++) {
    const float dd = (fabsf(d) < 1e-20f) ? -1e-20f : d;
    d = (a[i]-sig) - b2[i-1]*fast_rcp(dd);
    n += (d < 0.f) ? 1 : 0;
  }
  return n;
}

__device__ inline float dguard(float d) {
  if (fabsf(d) < 1e-12f) return (d < 0.f) ? -1e-12f : 1e-12f;
  return d;
}

// ---------------------------------------------------------------------------
// K4: fused per-batch eigen stage. grid 16, 256 threads, 129.5 KB LDS.
// Post-H tail (tridiag/twisted/chol32/backtransform) runs ENTIRELY on wave 0
// with zero barriers (intra-wave LDS fences only). H stored at stride 65
// (odd) so row reads at lane-stride are bank-conflict-free.
// ---------------------------------------------------------------------------
__global__ __launch_bounds__(256) void k_eigall(const float* __restrict__ G32g,
                                                const float* __restrict__ Gsg,
                                                float* __restrict__ Mg) {
  const int b = blockIdx.x;
  const int t = threadIdx.x;
  __shared__ float W0l[192*68];   // 13056 floats
  __shared__ float W1l[192*68];   // 13056
  __shared__ float scr[32*193];   // 6176: S1/Gt, then SH(64x65)+tridiag vecs
  __shared__ float rdv[64];
  __shared__ float pdv[16];
  __shared__ float misc[8];
  const float* Gb  = G32g + (size_t)b*JD*JD;
  const float* Gsb = Gsg  + (size_t)b*JD*JD;
  float* Mb = Mg + (size_t)b*JD*JD;

  // ---- stage 1: subspace basis (span of Gs^64 * E64) ----
  for (int f=t; f<JD*64; f+=256)
    W0l[(f>>6)*68 + (f&63)] = Gb[(f>>6)*JD + (f&63)];
  __syncthreads();
  orth_lds(W0l, scr, rdv, pdv, misc, t, 1e-6f);   // span-preserving (ridged)
  mm_lds(Gb, W0l, W1l, scr, t);                   // power +32
  orth_lds(W1l, scr, rdv, pdv, misc, t, 1e-6f);
  orth_lds(W1l, scr, rdv, pdv, misc, t, 0.f);     // CholQR2 clean pass

  // ---- H = W^T Gs W  (T1 = Gs*W into W0l; H -> scr stride 65) ----
  mm_lds(Gsb, W1l, W0l, scr, t);
  hgemm_lds(W1l, W0l, scr, 65, t);

  // ---- overlay pointers ----
  float* SH   = scr;               // H / reflectors, 64x65 = 4160
  float* a64  = scr + 4160;
  float* b2v  = scr + 4224;
  float* bsg  = scr + 4288;
  float* v0s  = scr + 4352;
  float* bts  = scr + 4416;
  float* vvec = scr + 4480;
  float* wvec = scr + 4544;        // ends 4608 < 6176
  float* Vt   = W0l;               // 64x36 = 2304
  float* dpA  = W0l + 2304;        // 64x33 = 2112
  float* dmA  = W0l + 4416;        // 64x33 = 2112 (ends 6528)
  float* lam  = W0l + 6560;        // 32

  // =========================================================================
  // wave-0 tail #1: Householder tridiag (no barriers) + Gershgorin bounds
  // =========================================================================
  if (t < 64) {
    for (int j=0; j<=61; j++) {
      const int m = 63 - j;
      const bool act = (t < m);
      const float xi = act ? SH[j*65 + (j+1+t)] : 0.f;
      float nr = xi*xi;
#pragma unroll
      for (int o=1;o<64;o<<=1) nr += __shfl_xor(nr, o);
      const float sig = sqrtf(nr);
      const float alpha = __shfl(xi, 0);
      const float sgn = (alpha >= 0.f) ? 1.f : -1.f;
      const float v0 = alpha + sgn*sig;
      const float beta = (sig > 1e-20f) ? 1.0f/(sig*fabsf(v0)) : 0.f;
      const float vt = (t==0) ? v0 : xi;
      if (act) vvec[t] = vt;
      if (t == 0) {
        a64[j] = SH[j*65+j]; b2v[j] = nr; bsg[j] = -sgn*sig;
        v0s[j] = v0; bts[j] = beta;
      }
      lds_fence();
      float pv = 0.f;
      if (act) {
        const float* row = SH + (j+1+t)*65 + (j+1);
        for (int c=0;c<m;c++) pv += row[c]*vvec[c];
        pv *= beta;
      }
      float dp = act ? vt*pv : 0.f;
#pragma unroll
      for (int o=1;o<64;o<<=1) dp += __shfl_xor(dp, o);
      const float gamma = 0.5f*beta*dp;
      const float wt = pv - gamma*vt;
      if (act) wvec[t] = wt;
      lds_fence();
      if (act) {
        float* row = SH + (j+1+t)*65 + (j+1);
        for (int c=0;c<m;c++) row[c] -= vt*wvec[c] + wt*vvec[c];
      }
      lds_fence();
    }
    if (t == 0) {
      a64[62] = SH[62*65+62];
      a64[63] = SH[63*65+63];
      const float bb = SH[62*65+63];
      b2v[62] = bb*bb;
      bsg[62] = bb;
    }
    lds_fence();
    // Gershgorin spectrum bounds
    {
      const float bl = (t>0)  ? sqrtf(b2v[t-1]) : 0.f;
      const float br = (t<63) ? sqrtf(b2v[t])   : 0.f;
      float lo = a64[t] - bl - br, hi = a64[t] + bl + br;
#pragma unroll
      for (int o=1;o<64;o<<=1) {
        lo = fminf(lo, __shfl_xor(lo,o));
        hi = fmaxf(hi, __shfl_xor(hi,o));
      }
      if (t == 0) { misc[0] = lo - 1e-4f; misc[1] = hi + 1e-4f; }
    }
  }
  __syncthreads();

  // ---- 9-section search: 8 probes/eig, all 256 threads, barrier-free ----
  {
    const int l = t >> 3, g = t & 7;
    const int r = 32 + l;
    float L = misc[0], H = misc[1];
    for (int it=0; it<10; it++) {
      const float mid = L + (H-L)*((float)(g+1)*(1.0f/9.0f));
      const int cnt = sturm_cnt_fast(a64, b2v, mid);
      float nL = L, nH = H;
#pragma unroll
      for (int k=0;k<8;k++) {
        const int ck = __shfl(cnt, k, 8);
        const float pk = L + (H-L)*((float)(k+1)*(1.0f/9.0f));
        if (ck <= r) nL = fmaxf(nL, pk); else nH = fminf(nH, pk);
      }
      L = nL; H = nH;
    }
    if (g == 0) lam[l] = 0.5f*(L+H);
  }
  __syncthreads();

  // ---- twisted-factorization inverse iteration (lane l = one eigvec) ----
  if (t < 32) {
    const int l = t;
    const float lm = lam[l];
    float d = dguard(a64[0] - lm);
    dpA[0*33+l] = d;
    for (int i=1;i<64;i++) {
      d = dguard((a64[i]-lm) - b2v[i-1]*fast_rcp(d));
      dpA[i*33+l] = d;
    }
    float e = dguard(a64[63] - lm);
    dmA[63*33+l] = e;
    for (int i=62;i>=0;i--) {
      e = dguard((a64[i]-lm) - b2v[i]*fast_rcp(e));
      dmA[i*33+l] = e;
    }
    int ks = 0; float gbest = 1e30f;
    for (int i=0;i<64;i++) {
      const float g = fabsf(dpA[i*33+l] + dmA[i*33+l] - (a64[i]-lm));
      if (g < gbest) { gbest = g; ks = i; }
    }
    Vt[ks*36+l] = 1.f;
    float z = 1.f;
    for (int i=ks-1;i>=0;i--) {
      z = -(bsg[i]*z) * fast_rcp(dpA[i*33+l]);
      z = fminf(fmaxf(z, -1e18f), 1e18f);
      Vt[i*36+l] = z;
    }
    z = 1.f;
    for (int i=ks+1;i<64;i++) {
      z = -(bsg[i-1]*z) * fast_rcp(dmA[i*33+l]);
      z = fminf(fmaxf(z, -1e18f), 1e18f);
      Vt[i*36+l] = z;
    }
    float nr2 = 0.f;
    for (int i=0;i<64;i++) { const float zz = Vt[i*36+l]; nr2 += zz*zz; }
    const float inv = rsqrtf(nr2);
    for (int i=0;i<64;i++) Vt[i*36+l] *= inv;
  }
  __syncthreads();

  // ---- CholQR-32 Gram (256 threads) ----
  for (int f=t; f<1024; f+=256) {
    const int i = f>>5, j = f&31;
    float s = 0.f;
    for (int r=0;r<64;r++) s += Vt[r*36+i]*Vt[r*36+j];
    dpA[i*33+j] = s;
  }
  __syncthreads();

  // =========================================================================
  // wave-0 tail #2: chol32 + trisolve + Householder backtransform (no barriers)
  // =========================================================================
  if (t < 64) {
    // ridge threshold from max diagonal
    {
      float dmx = (t < 32) ? dpA[t*33+t] : 0.f;
#pragma unroll
      for (int o=1;o<64;o<<=1) dmx = fmaxf(dmx, __shfl_xor(dmx, o));
      if (t < 32) dpA[t*33+t] += dmx * 1e-7f;
      lds_fence();
    }
    // LDL-form Cholesky-32
    for (int j=0;j<31;j++) {
      const float invd = fast_rcp(dpA[j*33+j]);
      for (int f=t; f<(31-j)*32; f+=64) {
        const int i = j+1 + (f>>5);
        const int k = f & 31;
        if (k > j && k <= i)
          dpA[i*33+k] -= dpA[i*33+j]*dpA[k*33+j]*invd;
      }
      lds_fence();
    }
    if (t < 32) rdv[t] = rsqrtf(dpA[t*33+t]);
    lds_fence();
    for (int f=t; f<1024; f+=64) {
      const int i = f>>5, k = f&31;
      if (k < i) dpA[i*33+k] *= rdv[k];
    }
    lds_fence();
    // trisolve rows of Vt (64 rows, one per lane)
    {
      float w[32];
#pragma unroll
      for (int c=0;c<32;c++) w[c] = Vt[t*36+c];
#pragma unroll
      for (int c=0;c<32;c++) {
        float v = w[c];
#pragma unroll
        for (int k=0;k<c;k++) v -= w[k]*dpA[c*33+k];
        w[c] = v * rdv[c];
      }
#pragma unroll
      for (int c=0;c<32;c++) Vt[t*36+c] = w[c];
    }
    lds_fence();
    // backtransform: V = H_0 H_1 ... H_61 Vt ; lane (g,c): g=t>>5, c=t&31
    {
      const int c = t & 31, g = t >> 5;
      for (int j=61; j>=0; j--) {
        const int m = 63 - j;
        float s = 0.f;
        for (int r=g; r<m; r+=2) {
          const float vr = (r==0) ? v0s[j] : SH[j*65 + (j+1+r)];
          s += vr * Vt[(j+1+r)*36 + c];
        }
        s += __shfl_xor(s, 32);
        const float wc = s * bts[j];
        for (int r=g; r<m; r+=2) {
          const float vr = (r==0) ? v0s[j] : SH[j*65 + (j+1+r)];
          Vt[(j+1+r)*36 + c] -= vr * wc;
        }
        lds_fence();
      }
    }
  }
  __syncthreads();

  // ---- B^T = (W * V)^T -> Bt (32 x 192, stride 193, overlays scr) ----
  float* Bt = scr;   // SH/reflectors/tridiag vecs all dead now
  if (t < JD) {
    float accv[32];
#pragma unroll
    for (int c=0;c<32;c++) accv[c] = 0.f;
    const float4* crow = (const float4*)(W1l + t*68);
#pragma unroll 2
    for (int kb=0; kb<16; kb++) {
      const float4 av = crow[kb];
      const float a4[4] = {av.x, av.y, av.z, av.w};
#pragma unroll
      for (int ki=0; ki<4; ki++) {
        const float aa = a4[ki];
        const float* vrow = Vt + (kb*4+ki)*36;
        const float4 v0 = *(const float4*)(vrow+0);
        const float4 v1 = *(const float4*)(vrow+4);
        const float4 v2 = *(const float4*)(vrow+8);
        const float4 v3 = *(const float4*)(vrow+12);
        const float4 v4 = *(const float4*)(vrow+16);
        const float4 v5 = *(const float4*)(vrow+20);
        const float4 v6 = *(const float4*)(vrow+24);
        const float4 v7 = *(const float4*)(vrow+28);
        accv[0]+=aa*v0.x; accv[1]+=aa*v0.y; accv[2]+=aa*v0.z; accv[3]+=aa*v0.w;
        accv[4]+=aa*v1.x; accv[5]+=aa*v1.y; accv[6]+=aa*v1.z; accv[7]+=aa*v1.w;
        accv[8]+=aa*v2.x; accv[9]+=aa*v2.y; accv[10]+=aa*v2.z; accv[11]+=aa*v2.w;
        accv[12]+=aa*v3.x; accv[13]+=aa*v3.y; accv[14]+=aa*v3.z; accv[15]+=aa*v3.w;
        accv[16]+=aa*v4.x; accv[17]+=aa*v4.y; accv[18]+=aa*v4.z; accv[19]+=aa*v4.w;
        accv[20]+=aa*v5.x; accv[21]+=aa*v5.y; accv[22]+=aa*v5.z; accv[23]+=aa*v5.w;
        accv[24]+=aa*v6.x; accv[25]+=aa*v6.y; accv[26]+=aa*v6.z; accv[27]+=aa*v6.w;
        accv[28]+=aa*v7.x; accv[29]+=aa*v7.y; accv[30]+=aa*v7.z; accv[31]+=aa*v7.w;
      }
    }
#pragma unroll
    for (int c=0;c<32;c++) Bt[c*193 + t] = accv[c];
  }
  __syncthreads();

  // ---- M = B B^T (192x192) -> global ----
  for (int tt=t; tt<576; tt+=256) {
    const int tr = tt/24, tc = tt - tr*24;
    const int r0 = tr*8, c0 = tc*8;
    float acc2[8][8];
#pragma unroll
    for (int i=0;i<8;i++)
#pragma unroll
      for (int j=0;j<8;j++) acc2[i][j]=0.f;
    for (int k=0;k<32;k++) {
      const float* br = Bt + k*193;
      const float4 a0 = *(const float4*)(br + r0);
      const float4 a1 = *(const float4*)(br + r0 + 4);
      const float4 b0 = *(const float4*)(br + c0);
      const float4 b1 = *(const float4*)(br + c0 + 4);
      const float va[8] = {a0.x,a0.y,a0.z,a0.w,a1.x,a1.y,a1.z,a1.w};
      const float vb[8] = {b0.x,b0.y,b0.z,b0.w,b1.x,b1.y,b1.z,b1.w};
#pragma unroll
      for (int i=0;i<8;i++)
#pragma unroll
        for (int j=0;j<8;j++) acc2[i][j] += va[i]*vb[j];
    }
#pragma unroll
    for (int i=0;i<8;i++)
#pragma unroll
      for (int j=0;j<8;j++)
        Mb[(r0+i)*JD + c0+j] = acc2[i][j];
  }
}

// ---------------------------------------------------------------------------
// K5: recon = A * M, fused depatchify. grid (128 patch-blocks, 16 batches).
// ---------------------------------------------------------------------------
__global__ __launch_bounds__(256) void k_recon(const float* __restrict__ x,
                                               const float* __restrict__ Mg,
                                               float* __restrict__ out) {
  const int nb = blockIdx.x;
  const int b  = blockIdx.y;
  const int t  = threadIdx.x;
  __shared__ float At[32][17];
  __shared__ float Mt[16][JD];
  const float* xb = x + (size_t)b*3*IMG*IMG;
  const float* Mb = Mg + (size_t)b*JD*JD;
  float* ob = out + (size_t)b*3*IMG*IMG;
  const int pg = t >> 4;
  const int jg = t & 15;
  float acc[2][12];
#pragma unroll
  for (int i=0;i<2;i++)
#pragma unroll
    for (int j=0;j<12;j++) acc[i][j]=0.f;
  for (int j0=0; j0<JD; j0+=16) {
    for (int f=t; f<512; f+=256) {
      const int nl = f >> 4, jj = f & 15;
      const int j = j0 + jj;
      const int n = nb*32 + nl;
      const int hh = n >> 6, ww = n & 63;
      const int c = j >> 6, p = (j >> 3) & 7, q = j & 7;
      At[nl][jj] = xb[(c*IMG + hh*8+p)*IMG + ww*8 + q];
    }
    for (int f=t; f<768; f+=256) {
      const int jj = f/48, cc = (f - jj*48)*4;
      *(float4*)(&Mt[jj][cc]) = *(const float4*)(Mb + (size_t)(j0+jj)*JD + cc);
    }
    __syncthreads();
#pragma unroll 4
    for (int jj=0;jj<16;jj++) {
      const float a0 = At[pg*2+0][jj];
      const float a1 = At[pg*2+1][jj];
      const float4 m0 = *(const float4*)(&Mt[jj][jg*12]);
      const float4 m1 = *(const float4*)(&Mt[jj][jg*12+4]);
      const float4 m2 = *(const float4*)(&Mt[jj][jg*12+8]);
      const float mm[12] = {m0.x,m0.y,m0.z,m0.w,m1.x,m1.y,m1.z,m1.w,
                            m2.x,m2.y,m2.z,m2.w};
#pragma unroll
      for (int j=0;j<12;j++) {
        acc[0][j] += a0*mm[j];
        acc[1][j] += a1*mm[j];
      }
    }
    __syncthreads();
  }
#pragma unroll
  for (int i=0;i<2;i++) {
    const int n = nb*32 + pg*2 + i;
    const int hh = n >> 6, ww = n & 63;
#pragma unroll
    for (int j4=0;j4<3;j4++) {
      const int jo = jg*12 + j4*4;
      const int c = jo >> 6, p = (jo >> 3) & 7, q = jo & 7;
      const float4 v = make_float4(acc[i][j4*4+0], acc[i][j4*4+1],
                                   acc[i][j4*4+2], acc[i][j4*4+3]);
      *(float4*)(ob + (size_t)(c*IMG + hh*8+p)*IMG + ww*8 + q) = v;
    }
  }
}

// ---------------------------------------------------------------------------
extern "C" void kernel_launch(void* const* d_in, const int* in_sizes, int n_in,
                              void* d_out, int out_size, void* d_ws, size_t ws_size,
                              hipStream_t stream) {
  (void)in_sizes; (void)n_in; (void)out_size; (void)ws_size;
  const float* x = (const float*)d_in[0];
  float* out = (float*)d_out;
  float* ws  = (float*)d_ws;

  float* part = ws;                    // dead after k_greduce
  float* Gs   = ws + 2359296;
  float* P0   = ws + 2949120;
  float* P1   = ws + 3538944;
  float* Mg   = ws;                    // overlay on dead part region

  k_gram  <<<dim3(4,4,16), 256, 0, stream>>>(x, part);
  k_greduce<<<2304,        256, 0, stream>>>(part, Gs);
  k_sq    <<<dim3(6,16),   256, 0, stream>>>(Gs, P0);   // Gs^2
  k_sq    <<<dim3(6,16),   256, 0, stream>>>(P0, P1);   // Gs^4
  k_sq    <<<dim3(6,16),   256, 0, stream>>>(P1, P0);   // Gs^8
  k_sq    <<<dim3(6,16),   256, 0, stream>>>(P0, P1);   // Gs^16
  k_sq    <<<dim3(6,16),   256, 0, stream>>>(P1, P0);   // Gs^32
  k_eigall<<<16,           256, 0, stream>>>(P0, Gs, Mg);
  k_recon <<<dim3(128,16), 256, 0, stream>>>(x, Mg, out);
}

// Round 6
// 982.950 us; speedup vs baseline: 1.0794x; 1.0794x over previous
//
#include <hip/hip_runtime.h>
#include <cstdint>
#include <cstddef>

#define IMG 512
#define JD 192

__device__ inline float fast_rcp(float x) { return __builtin_amdgcn_rcpf(x); }

// ---------------------------------------------------------------------------
// K1: partial Gram. grid (4 patch-chunks, 4 row-slabs, 16 batches), 256 thr.
// ---------------------------------------------------------------------------
__global__ __launch_bounds__(256) void k_gram(const float* __restrict__ x,
                                              float* __restrict__ part) {
  const int ck = blockIdx.x;
  const int sl = blockIdx.y;
  const int b  = blockIdx.z;
  const int t  = threadIdx.x;
  __shared__ float tile[32][JD];
  const int ty = t >> 5;
  const int tx = t & 31;
  const int r0 = sl*48 + ty*6;
  const int c0 = tx*6;
  float acc[6][6];
#pragma unroll
  for (int i=0;i<6;i++)
#pragma unroll
    for (int j=0;j<6;j++) acc[i][j]=0.f;
  const float* xb = x + (size_t)b*3*IMG*IMG;
  const int nbeg = ck*1024;
  for (int n0 = nbeg; n0 < nbeg+1024; n0 += 32) {
    for (int f = t; f < 32*JD; f += 256) {
      const int nl = f / JD, j = f - nl*JD;
      const int n = n0 + nl;
      const int hh = n >> 6, ww = n & 63;
      const int c = j >> 6, p = (j >> 3) & 7, q = j & 7;
      tile[nl][j] = xb[(c*IMG + hh*8+p)*IMG + ww*8 + q];
    }
    __syncthreads();
#pragma unroll 4
    for (int nl = 0; nl < 32; nl++) {
      float va[6], vb[6];
#pragma unroll
      for (int i=0;i<6;i++) va[i] = tile[nl][r0+i];
#pragma unroll
      for (int j=0;j<6;j++) vb[j] = tile[nl][c0+j];
#pragma unroll
      for (int i=0;i<6;i++)
#pragma unroll
        for (int j=0;j<6;j++) acc[i][j] += va[i]*vb[j];
    }
    __syncthreads();
  }
  float* dst = part + (((size_t)(b*4 + sl))*4 + ck) * (size_t)(48*JD);
#pragma unroll
  for (int i=0;i<6;i++)
#pragma unroll
    for (int j=0;j<6;j++)
      dst[(ty*6+i)*JD + c0+j] = acc[i][j];
}

// ---------------------------------------------------------------------------
// K2: reduce 4 chunk-partials -> Gs = G / 4096
// ---------------------------------------------------------------------------
__global__ __launch_bounds__(256) void k_greduce(const float* __restrict__ part,
                                                 float* __restrict__ Gs) {
  const int idx = blockIdx.x*256 + threadIdx.x;
  const int b = idx / (JD*JD);
  const int e = idx - b*(JD*JD);
  const int r = e / JD;
  const int sl = r / 48;
  const int w = (r - sl*48)*JD + (e - r*JD);
  const float* p = part + ((size_t)(b*4+sl))*4*(48*JD) + w;
  float s = 0.f;
#pragma unroll
  for (int ck=0; ck<4; ck++) s += p[(size_t)ck*48*JD];
  Gs[idx] = s * (1.0f/4096.0f);
}

// ---------------------------------------------------------------------------
// K3: D = S*S for symmetric S (per batch), lower-tri tile pairs.
// ---------------------------------------------------------------------------
__global__ __launch_bounds__(256) void k_sq(const float* __restrict__ S,
                                            float* __restrict__ D) {
  const int tp = blockIdx.x;
  const int b  = blockIdx.y;
  int ti, tj;
  if      (tp==0){ti=0;tj=0;} else if (tp==1){ti=1;tj=0;}
  else if (tp==2){ti=1;tj=1;} else if (tp==3){ti=2;tj=0;}
  else if (tp==4){ti=2;tj=1;} else            {ti=2;tj=2;}
  const float* Sb = S + (size_t)b*JD*JD;
  float* Db = D + (size_t)b*JD*JD;
  __shared__ float Ar[64][33];
  __shared__ float Br[64][33];
  const int t = threadIdx.x;
  const int ty = t >> 4, tx = t & 15;
  float acc[4][4];
#pragma unroll
  for (int i=0;i<4;i++)
#pragma unroll
    for (int j=0;j<4;j++) acc[i][j]=0.f;
  for (int k0=0; k0<JD; k0+=32) {
    for (int f=t; f<2048; f+=256) {
      const int row = f >> 5, kk = f & 31;
      Ar[row][kk] = Sb[(ti*64+row)*JD + k0+kk];
      Br[row][kk] = Sb[(tj*64+row)*JD + k0+kk];
    }
    __syncthreads();
#pragma unroll 4
    for (int k=0;k<32;k++) {
      float va[4], vb[4];
#pragma unroll
      for (int i=0;i<4;i++) va[i] = Ar[ty*4+i][k];
#pragma unroll
      for (int j=0;j<4;j++) vb[j] = Br[tx*4+j][k];
#pragma unroll
      for (int i=0;i<4;i++)
#pragma unroll
        for (int j=0;j<4;j++) acc[i][j] += va[i]*vb[j];
    }
    __syncthreads();
  }
#pragma unroll
  for (int i=0;i<4;i++)
#pragma unroll
    for (int j=0;j<4;j++) {
      const int r = ti*64+ty*4+i, c = tj*64+tx*4+j;
      Db[r*JD+c] = acc[i][j];
      if (ti != tj) Db[c*JD+r] = acc[i][j];
    }
}

// ---------------------------------------------------------------------------
// LDS-resident helpers (256 threads). W buffers: 192 rows, stride 68 floats.
// ---------------------------------------------------------------------------

// In-place ridge-CholQR of Wl (192x68 LDS). S1 is 64x68 LDS scratch.
__device__ void orth_lds(float* __restrict__ Wl, float* __restrict__ S1,
                         float* __restrict__ rdv, float* __restrict__ pdv,
                         float* __restrict__ misc, int t, float ridge) {
  const int ty = t >> 4, tx = t & 15;
  float acc[4][4];
#pragma unroll
  for (int i=0;i<4;i++)
#pragma unroll
    for (int j=0;j<4;j++) acc[i][j]=0.f;
  __syncthreads();
  // ---- Gram: S1 = W^T W ----
#pragma unroll 2
  for (int r=0; r<JD; r++) {
    const float4 va4 = *(const float4*)(Wl + r*68 + ty*4);
    const float4 vb4 = *(const float4*)(Wl + r*68 + tx*4);
    const float a4[4] = {va4.x, va4.y, va4.z, va4.w};
    const float b4[4] = {vb4.x, vb4.y, vb4.z, vb4.w};
#pragma unroll
    for (int i=0;i<4;i++)
#pragma unroll
      for (int j=0;j<4;j++) acc[i][j] += a4[i]*b4[j];
  }
#pragma unroll
  for (int i=0;i<4;i++)
#pragma unroll
    for (int j=0;j<4;j++)
      S1[(ty*4+i)*68 + tx*4+j] = acc[i][j];
  __syncthreads();
  // ---- ridge ----
  if (ridge > 0.f) {
    if (t < 64) {
      float d = S1[t*68+t];
#pragma unroll
      for (int o=1;o<64;o<<=1) d = fmaxf(d, __shfl_xor(d, o));
      if (t == 0) misc[0] = d * ridge;
    }
    __syncthreads();
    if (t < 64) S1[t*68+t] += misc[0];
    __syncthreads();
  }
  // ---- blocked Cholesky (LDL-form, panel = 16) ----
  for (int p=0; p<4; p++) {
    const int b16 = p*16;
    // phase A: diagonal 16x16 factor, single wave, no barriers
    if (t < 64) {
      for (int jj=0; jj<16; jj++) {
        const int j = b16 + jj;
        const float invd = fast_rcp(S1[j*68+j]);
        if (t == 0) pdv[jj] = invd;
        const int nit = (15-jj)*16;
        for (int f=t; f<nit; f+=64) {
          const int i = j+1 + (f>>4);
          const int k = j+1 + (f&15);
          if (k <= i)
            S1[i*68+k] -= S1[i*68+j]*S1[k*68+j]*invd;
        }
      }
    }
    __syncthreads();
    // phase B: panel rows below diag block, one thread per row (registers)
    const int rb = b16 + 16;
    if (t < 64 - rb) {
      const int r = rb + t;
      float pr[16];
      float4* prp = (float4*)pr;
      prp[0] = *(const float4*)(S1 + r*68 + b16);
      prp[1] = *(const float4*)(S1 + r*68 + b16 + 4);
      prp[2] = *(const float4*)(S1 + r*68 + b16 + 8);
      prp[3] = *(const float4*)(S1 + r*68 + b16 + 12);
#pragma unroll
      for (int c=1; c<16; c++) {
        float s = pr[c];
#pragma unroll
        for (int j=0; j<c; j++) s -= pr[j]*S1[(b16+c)*68 + b16+j]*pdv[j];
        pr[c] = s;
      }
      *(float4*)(S1 + r*68 + b16)      = prp[0];
      *(float4*)(S1 + r*68 + b16 + 4)  = prp[1];
      *(float4*)(S1 + r*68 + b16 + 8)  = prp[2];
      *(float4*)(S1 + r*68 + b16 + 12) = prp[3];
    }
    __syncthreads();
    // phase C: trailing rank-16 update, fully parallel
    for (int f=t; f<2304; f+=256) {
      const int i = rb + f/48;
      const int k = rb + (f - (f/48)*48);
      if (i < 64 && k < 64 && k <= i) {
        float s = S1[i*68+k];
#pragma unroll
        for (int jj=0; jj<16; jj++)
          s -= S1[i*68 + b16+jj]*S1[k*68 + b16+jj]*pdv[jj];
        S1[i*68+k] = s;
      }
    }
    __syncthreads();
  }
  // ---- scale columns, triangular solve in registers ----
  if (t < 64) rdv[t] = rsqrtf(S1[t*68+t]);
  __syncthreads();
  for (int f=t; f<4096; f+=256) {
    const int i = f>>6, k = f&63;
    if (k < i) S1[i*68+k] *= rdv[k];
  }
  __syncthreads();
  if (t < JD) {
    float w[64];
    float4* wp = (float4*)w;
#pragma unroll
    for (int c4=0;c4<16;c4++) wp[c4] = *(const float4*)(Wl + t*68 + c4*4);
#pragma unroll
    for (int c=0;c<64;c++) {
      float v = w[c];
#pragma unroll
      for (int k=0;k<c;k++) v -= w[k]*S1[c*68+k];
      w[c] = v * rdv[c];
    }
#pragma unroll
    for (int c4=0;c4<16;c4++) *(float4*)(Wl + t*68 + c4*4) = wp[c4];
  }
  __syncthreads();
}

// Wout(192x68 LDS) = G(192x192 global) * Win(192x68 LDS); Gt 32x193 scratch
__device__ void mm_lds(const float* __restrict__ G, const float* __restrict__ Win,
                       float* __restrict__ Wout, float* __restrict__ Gt, int t) {
  const int rg = t >> 2, cg = t & 3;
  float acc[3][16];
#pragma unroll
  for (int i=0;i<3;i++)
#pragma unroll
    for (int j=0;j<16;j++) acc[i][j]=0.f;
  for (int k0=0; k0<JD; k0+=32) {
    __syncthreads();
    for (int f=t; f<6144; f+=256) {
      const int r = f >> 5, kk = f & 31;
      Gt[kk*193 + r] = G[r*JD + k0 + kk];
    }
    __syncthreads();
#pragma unroll 2
    for (int k=0;k<32;k++) {
      const float a0 = Gt[k*193 + rg*3+0];
      const float a1 = Gt[k*193 + rg*3+1];
      const float a2 = Gt[k*193 + rg*3+2];
      const float* wr = Win + (k0+k)*68 + cg*16;
#pragma unroll
      for (int j4=0;j4<4;j4++) {
        const float4 b4 = *(const float4*)(wr + 4*j4);
        const float bb[4] = {b4.x, b4.y, b4.z, b4.w};
#pragma unroll
        for (int jj=0;jj<4;jj++) {
          acc[0][j4*4+jj] += a0*bb[jj];
          acc[1][j4*4+jj] += a1*bb[jj];
          acc[2][j4*4+jj] += a2*bb[jj];
        }
      }
    }
  }
  __syncthreads();
#pragma unroll
  for (int i=0;i<3;i++)
#pragma unroll
    for (int j=0;j<16;j++)
      Wout[(rg*3+i)*68 + cg*16 + j] = acc[i][j];
  __syncthreads();
}

// S1 = X^T * Y (both 192x68 LDS), dst stride ss
__device__ void hgemm_lds(const float* __restrict__ X, const float* __restrict__ Y,
                          float* __restrict__ S1, int ss, int t) {
  const int ty = t >> 4, tx = t & 15;
  float acc[4][4];
#pragma unroll
  for (int i=0;i<4;i++)
#pragma unroll
    for (int j=0;j<4;j++) acc[i][j]=0.f;
#pragma unroll 2
  for (int r=0; r<JD; r++) {
    const float4 va4 = *(const float4*)(X + r*68 + ty*4);
    const float4 vb4 = *(const float4*)(Y + r*68 + tx*4);
    const float a4[4] = {va4.x, va4.y, va4.z, va4.w};
    const float b4[4] = {vb4.x, vb4.y, vb4.z, vb4.w};
#pragma unroll
    for (int i=0;i<4;i++)
#pragma unroll
      for (int j=0;j<4;j++) acc[i][j] += a4[i]*b4[j];
  }
  __syncthreads();
#pragma unroll
  for (int i=0;i<4;i++)
#pragma unroll
    for (int j=0;j<4;j++)
      S1[(ty*4+i)*ss + tx*4+j] = acc[i][j];
  __syncthreads();
}

// ---------------------------------------------------------------------------
// K4a: subspace basis + H, all W traffic in LDS. grid 16, 256 thr.
// Outputs: WbG (192x64 row-major), Hgg (64x65-strided).
// ---------------------------------------------------------------------------
__global__ __launch_bounds__(256) void k_subH(const float* __restrict__ G32g,
                                              const float* __restrict__ Gsg,
                                              float* __restrict__ WbG,
                                              float* __restrict__ Hgg) {
  const int b = blockIdx.x;
  const int t = threadIdx.x;
  __shared__ float W0l[192*68];
  __shared__ float W1l[192*68];
  __shared__ float scr[32*193];   // unions: S1 (64x68) / Gt (32x193) / H (64x65)
  __shared__ float rdv[64];
  __shared__ float pdv[16];
  __shared__ float misc[8];
  const float* Gb  = G32g + (size_t)b*JD*JD;
  const float* Gsb = Gsg  + (size_t)b*JD*JD;

  for (int f=t; f<JD*64; f+=256)
    W0l[(f>>6)*68 + (f&63)] = Gb[(f>>6)*JD + (f&63)];
  __syncthreads();

  orth_lds(W0l, scr, rdv, pdv, misc, t, 1e-6f);   // span-preserving (ridged)
  mm_lds(Gb, W0l, W1l, scr, t);                   // power +32
  orth_lds(W1l, scr, rdv, pdv, misc, t, 1e-6f);
  orth_lds(W1l, scr, rdv, pdv, misc, t, 0.f);     // CholQR2 clean pass

  // H = W^T Gs W  (T1 = Gs*W into W0l, then hgemm -> scr at stride 65)
  mm_lds(Gsb, W1l, W0l, scr, t);
  hgemm_lds(W1l, W0l, scr, 65, t);

  float* Wb = WbG + (size_t)b*JD*64;
  for (int f=t; f<JD*64; f+=256)
    Wb[f] = W1l[(f>>6)*68 + (f&63)];
  float* Hb = Hgg + (size_t)b*4160;
  for (int f=t; f<4160; f+=256) Hb[f] = scr[f];
}

// ---------------------------------------------------------------------------
// Householder tridiag of A (64x64, stride 65) in place (256-thread update).
// ---------------------------------------------------------------------------
__device__ void dev_tridiag(float* __restrict__ A, float* a, float* b2,
                            float* bsg, float* v0s, float* bts,
                            float* vvec, float* wvec, int t) {
  for (int j=0; j<=61; j++) {
    const int m = 63 - j;
    if (t < 64) {
      float xi = (t < m) ? A[j*65 + (j+1+t)] : 0.f;
      float nr = xi*xi;
#pragma unroll
      for (int o=1;o<64;o<<=1) nr += __shfl_xor(nr, o);
      const float sig = sqrtf(nr);
      const float alpha = __shfl(xi, 0);
      const float sgn = (alpha >= 0.f) ? 1.f : -1.f;
      const float v0 = alpha + sgn*sig;
      const float beta = (sig > 1e-20f) ? 1.0f/(sig*fabsf(v0)) : 0.f;
      if (t < m) vvec[t] = (t==0) ? v0 : xi;
      if (t == 0) {
        a[j] = A[j*65+j]; b2[j] = nr; bsg[j] = -sgn*sig;
        v0s[j] = v0; bts[j] = beta;
      }
      float pv = 0.f;
      if (t < m) {
        const float* row = A + (j+1+t)*65 + (j+1);
        for (int c=0;c<m;c++) pv += row[c]*vvec[c];
        pv *= beta;
      }
      float dp = (t<m) ? vvec[t]*pv : 0.f;
#pragma unroll
      for (int o=1;o<64;o<<=1) dp += __shfl_xor(dp, o);
      const float gamma = 0.5f*beta*dp;
      if (t < m) wvec[t] = pv - gamma*vvec[t];
    }
    __syncthreads();
    const int mm = m*m;
    for (int f=t; f<mm; f+=256) {
      const int r = f/m, c = f - r*m;
      A[(j+1+r)*65 + (j+1+c)] -= vvec[r]*wvec[c] + wvec[r]*vvec[c];
    }
    __syncthreads();
  }
  if (t == 0) {
    a[62] = A[62*65+62];
    a[63] = A[63*65+63];
    const float bb = A[62*65+63];
    b2[62] = bb*bb;
    bsg[62] = bb;
  }
  __syncthreads();
}

// ---------------------------------------------------------------------------
// K4b: tridiagonalize H. grid 16. Exports reflectors (in Hgg) + vec5.
// ---------------------------------------------------------------------------
__global__ __launch_bounds__(256) void k_trid(float* __restrict__ Hgg,
                                              float* __restrict__ vec5) {
  const int b = blockIdx.x;
  const int t = threadIdx.x;
  __shared__ float SH[4160];
  __shared__ float a64[64];
  __shared__ float b2v[64];
  __shared__ float bsg[64];
  __shared__ float v0s[64];
  __shared__ float bts[64];
  __shared__ float vvec[64];
  __shared__ float wvec[64];
  float* Hb = Hgg + (size_t)b*4160;
  for (int f=t; f<4160; f+=256) SH[f] = Hb[f];
  __syncthreads();
  dev_tridiag(SH, a64, b2v, bsg, v0s, bts, vvec, wvec, t);
  for (int f=t; f<4160; f+=256) Hb[f] = SH[f];   // reflectors back out
  float* vb = vec5 + (size_t)b*320;
  if (t < 64) {
    vb[t]     = a64[t];
    vb[64+t]  = b2v[t];
    vb[128+t] = bsg[t];
    vb[192+t] = v0s[t];
    vb[256+t] = bts[t];
  }
}

// Sturm count with fast reciprocal
__device__ inline int sturm_cnt_fast(const float* a, const float* b2, float sig) {
  float d = a[0] - sig;
  int n = (d < 0.f) ? 1 : 0;
#pragma unroll 8
  for (int i=1;i<64;i++) {
    const float dd = (fabsf(d) < 1e-20f) ? -1e-20f : d;
    d = (a[i]-sig) - b2[i-1]*fast_rcp(dd);
    n += (d < 0.f) ? 1 : 0;
  }
  return n;
}

__device__ inline float dguard(float d) {
  if (fabsf(d) < 1e-12f) return (d < 0.f) ? -1e-12f : 1e-12f;
  return d;
}

// ---------------------------------------------------------------------------
// K4c: eigenvalues (9-section Sturm) + twisted inverse iteration + CholQR32 +
// Householder backtransform. grid 16. Output Vt (64x32) -> VtG.
// ---------------------------------------------------------------------------
__global__ __launch_bounds__(256) void k_vec(const float* __restrict__ Hgg,
                                             const float* __restrict__ vec5,
                                             float* __restrict__ VtG) {
  const int b = blockIdx.x;
  const int t = threadIdx.x;
  __shared__ float SH[4160];
  __shared__ float Vt[64*36];
  __shared__ float dpA[64*33];
  __shared__ float dmA[64*33];
  __shared__ float ps[8*33];
  __shared__ float wvred[32];
  __shared__ float rdv[64];
  __shared__ float a64[64];
  __shared__ float b2v[64];
  __shared__ float bsg[64];
  __shared__ float v0s[64];
  __shared__ float bts[64];
  __shared__ float lam[32];
  __shared__ float misc[8];
  const float* Hb = Hgg + (size_t)b*4160;
  const float* vb = vec5 + (size_t)b*320;
  for (int f=t; f<4160; f+=256) SH[f] = Hb[f];   // issue early, used late
  if (t < 64) {
    a64[t] = vb[t];
    b2v[t] = vb[64+t];
    bsg[t] = vb[128+t];
    v0s[t] = vb[192+t];
    bts[t] = vb[256+t];
  }
  __syncthreads();

  // ---- spectrum bounds (Gershgorin) ----
  if (t < 64) {
    const float bl = (t>0)  ? sqrtf(b2v[t-1]) : 0.f;
    const float br = (t<63) ? sqrtf(b2v[t])   : 0.f;
    float lo = a64[t] - bl - br, hi = a64[t] + bl + br;
#pragma unroll
    for (int o=1;o<64;o<<=1) {
      lo = fminf(lo, __shfl_xor(lo,o));
      hi = fmaxf(hi, __shfl_xor(hi,o));
    }
    if (t == 0) { misc[0] = lo - 1e-4f; misc[1] = hi + 1e-4f; }
  }
  __syncthreads();

  // ---- 9-section search: 8 probes/eig in parallel, 10 rounds ----
  {
    const int l = t >> 3, g = t & 7;
    const int r = 32 + l;
    float L = misc[0], H = misc[1];
    for (int it=0; it<10; it++) {
      const float mid = L + (H-L)*((float)(g+1)*(1.0f/9.0f));
      const int cnt = sturm_cnt_fast(a64, b2v, mid);
      float nL = L, nH = H;
#pragma unroll
      for (int k=0;k<8;k++) {
        const int ck = __shfl(cnt, k, 8);
        const float pk = L + (H-L)*((float)(k+1)*(1.0f/9.0f));
        if (ck <= r) nL = fmaxf(nL, pk); else nH = fminf(nH, pk);
      }
      L = nL; H = nH;
    }
    if (g == 0) lam[l] = 0.5f*(L+H);
  }
  __syncthreads();

  // ---- twisted-factorization inverse iteration (lane l = one eigvec) ----
  if (t < 32) {
    const int l = t;
    const float lm = lam[l];
    float d = dguard(a64[0] - lm);
    dpA[0*33+l] = d;
    for (int i=1;i<64;i++) {
      d = dguard((a64[i]-lm) - b2v[i-1]*fast_rcp(d));
      dpA[i*33+l] = d;
    }
    float e = dguard(a64[63] - lm);
    dmA[63*33+l] = e;
    for (int i=62;i>=0;i--) {
      e = dguard((a64[i]-lm) - b2v[i]*fast_rcp(e));
      dmA[i*33+l] = e;
    }
    int ks = 0; float gbest = 1e30f;
    for (int i=0;i<64;i++) {
      const float g = fabsf(dpA[i*33+l] + dmA[i*33+l] - (a64[i]-lm));
      if (g < gbest) { gbest = g; ks = i; }
    }
    Vt[ks*36+l] = 1.f;
    float z = 1.f;
    for (int i=ks-1;i>=0;i--) {
      z = -(bsg[i]*z) * fast_rcp(dpA[i*33+l]);
      z = fminf(fmaxf(z, -1e18f), 1e18f);
      Vt[i*36+l] = z;
    }
    z = 1.f;
    for (int i=ks+1;i<64;i++) {
      z = -(bsg[i-1]*z) * fast_rcp(dmA[i*33+l]);
      z = fminf(fmaxf(z, -1e18f), 1e18f);
      Vt[i*36+l] = z;
    }
    float nr2 = 0.f;
    for (int i=0;i<64;i++) { const float zz = Vt[i*36+l]; nr2 += zz*zz; }
    const float inv = rsqrtf(nr2);
    for (int i=0;i<64;i++) Vt[i*36+l] *= inv;
  }
  __syncthreads();

  // ---- CholQR-32 safety pass on Vt ----
  for (int f=t; f<1024; f+=256) {
    const int i = f>>5, j = f&31;
    float s = 0.f;
    for (int r=0;r<64;r++) s += Vt[r*36+i]*Vt[r*36+j];
    dpA[i*33+j] = s;
  }
  __syncthreads();
  if (t == 0) {
    float m = 0.f;
    for (int j=0;j<32;j++) m = fmaxf(m, dpA[j*33+j]);
    misc[2] = m * 1e-7f;
  }
  __syncthreads();
  if (t < 32) dpA[t*33+t] += misc[2];
  for (int j=0;j<31;j++) {
    __syncthreads();
    const float invd = fast_rcp(dpA[j*33+j]);
    for (int f=t; f<(31-j)*32; f+=256) {
      const int i = j+1 + (f>>5);
      const int k = f & 31;
      if (k > j && k <= i)
        dpA[i*33+k] -= dpA[i*33+j]*dpA[k*33+j]*invd;
    }
  }
  __syncthreads();
  if (t < 32) rdv[t] = rsqrtf(dpA[t*33+t]);
  __syncthreads();
  for (int f=t; f<1024; f+=256) {
    const int i = f>>5, k = f&31;
    if (k < i) dpA[i*33+k] *= rdv[k];
  }
  __syncthreads();
  if (t < 64) {
    float w[32];
#pragma unroll
    for (int c=0;c<32;c++) w[c] = Vt[t*36+c];
#pragma unroll
    for (int c=0;c<32;c++) {
      float v = w[c];
#pragma unroll
      for (int k=0;k<c;k++) v -= w[k]*dpA[c*33+k];
      w[c] = v * rdv[c];
    }
#pragma unroll
    for (int c=0;c<32;c++) Vt[t*36+c] = w[c];
  }
  __syncthreads();

  // ---- backtransform: V = H_0 H_1 ... H_61 Vt ----
  for (int j=61; j>=0; j--) {
    const int m = 63 - j;
    {
      const int c = t & 31, g = t >> 5;
      float s = 0.f;
      for (int r=g; r<m; r+=8) {
        const float vr = (r==0) ? v0s[j] : SH[j*65 + (j+1+r)];
        s += vr * Vt[(j+1+r)*36 + c];
      }
      ps[g*33+c] = s;
    }
    __syncthreads();
    if (t < 32) {
      float s = 0.f;
#pragma unroll
      for (int g=0;g<8;g++) s += ps[g*33+t];
      wvred[t] = s * bts[j];
    }
    __syncthreads();
    {
      const int c = t & 31, g = t >> 5;
      for (int r=g; r<m; r+=8) {
        const float vr = (r==0) ? v0s[j] : SH[j*65 + (j+1+r)];
        Vt[(j+1+r)*36 + c] -= vr * wvred[c];
      }
    }
    __syncthreads();
  }

  float* Vb = VtG + (size_t)b*2048;
  for (int f=t; f<2048; f+=256) Vb[f] = Vt[(f>>5)*36 + (f&31)];
}

// ---------------------------------------------------------------------------
// K4d: B^T = (W*V)^T -> Btg (32 x 192 row-major per batch). grid 16.
// ---------------------------------------------------------------------------
__global__ __launch_bounds__(256) void k_bv(const float* __restrict__ WbG,
                                            const float* __restrict__ VtG,
                                            float* __restrict__ Btg) {
  const int b = blockIdx.x;
  const int t = threadIdx.x;
  __shared__ float Vt[64*36];
  const float* W = WbG + (size_t)b*JD*64;
  const float* Vb = VtG + (size_t)b*2048;
  float* Bt = Btg + (size_t)b*32*JD;
  for (int f=t; f<2048; f+=256) Vt[(f>>5)*36 + (f&31)] = Vb[f];
  __syncthreads();
  if (t < JD) {
    float accv[32];
#pragma unroll
    for (int c=0;c<32;c++) accv[c] = 0.f;
    const float4* crow = (const float4*)(W + t*64);
#pragma unroll 2
    for (int kb=0; kb<16; kb++) {
      const float4 av = crow[kb];
      const float a4[4] = {av.x, av.y, av.z, av.w};
#pragma unroll
      for (int ki=0; ki<4; ki++) {
        const float aa = a4[ki];
        const float* vrow = Vt + (kb*4+ki)*36;
        const float4 v0 = *(const float4*)(vrow+0);
        const float4 v1 = *(const float4*)(vrow+4);
        const float4 v2 = *(const float4*)(vrow+8);
        const float4 v3 = *(const float4*)(vrow+12);
        const float4 v4 = *(const float4*)(vrow+16);
        const float4 v5 = *(const float4*)(vrow+20);
        const float4 v6 = *(const float4*)(vrow+24);
        const float4 v7 = *(const float4*)(vrow+28);
        accv[0]+=aa*v0.x; accv[1]+=aa*v0.y; accv[2]+=aa*v0.z; accv[3]+=aa*v0.w;
        accv[4]+=aa*v1.x; accv[5]+=aa*v1.y; accv[6]+=aa*v1.z; accv[7]+=aa*v1.w;
        accv[8]+=aa*v2.x; accv[9]+=aa*v2.y; accv[10]+=aa*v2.z; accv[11]+=aa*v2.w;
        accv[12]+=aa*v3.x; accv[13]+=aa*v3.y; accv[14]+=aa*v3.z; accv[15]+=aa*v3.w;
        accv[16]+=aa*v4.x; accv[17]+=aa*v4.y; accv[18]+=aa*v4.z; accv[19]+=aa*v4.w;
        accv[20]+=aa*v5.x; accv[21]+=aa*v5.y; accv[22]+=aa*v5.z; accv[23]+=aa*v5.w;
        accv[24]+=aa*v6.x; accv[25]+=aa*v6.y; accv[26]+=aa*v6.z; accv[27]+=aa*v6.w;
        accv[28]+=aa*v7.x; accv[29]+=aa*v7.y; accv[30]+=aa*v7.z; accv[31]+=aa*v7.w;
      }
    }
#pragma unroll
    for (int c=0;c<32;c++) Bt[c*JD + t] = accv[c];
  }
}

// ---------------------------------------------------------------------------
// K4e: M = B B^T = Bt^T Bt, lower-tri tile pairs (like k_sq). grid (6,16).
// ---------------------------------------------------------------------------
__global__ __launch_bounds__(256) void k_mm(const float* __restrict__ Btg,
                                            float* __restrict__ Mg) {
  const int tp = blockIdx.x;
  const int b  = blockIdx.y;
  int ti, tj;
  if      (tp==0){ti=0;tj=0;} else if (tp==1){ti=1;tj=0;}
  else if (tp==2){ti=1;tj=1;} else if (tp==3){ti=2;tj=0;}
  else if (tp==4){ti=2;tj=1;} else            {ti=2;tj=2;}
  const float* Bt = Btg + (size_t)b*32*JD;
  float* Mb = Mg + (size_t)b*JD*JD;
  __shared__ float Ar[32][68];
  __shared__ float Br[32][68];
  const int t = threadIdx.x;
  const int ty = t >> 4, tx = t & 15;
  for (int f=t; f<2048; f+=256) {
    const int k = f >> 6, c = f & 63;
    Ar[k][c] = Bt[k*JD + ti*64 + c];
    Br[k][c] = Bt[k*JD + tj*64 + c];
  }
  __syncthreads();
  float acc[4][4];
#pragma unroll
  for (int i=0;i<4;i++)
#pragma unroll
    for (int j=0;j<4;j++) acc[i][j]=0.f;
#pragma unroll 4
  for (int k=0;k<32;k++) {
    const float4 va4 = *(const float4*)(&Ar[k][ty*4]);
    const float4 vb4 = *(const float4*)(&Br[k][tx*4]);
    const float a4[4] = {va4.x, va4.y, va4.z, va4.w};
    const float b4[4] = {vb4.x, vb4.y, vb4.z, vb4.w};
#pragma unroll
    for (int i=0;i<4;i++)
#pragma unroll
      for (int j=0;j<4;j++) acc[i][j] += a4[i]*b4[j];
  }
#pragma unroll
  for (int i=0;i<4;i++)
#pragma unroll
    for (int j=0;j<4;j++) {
      const int r = ti*64+ty*4+i, c = tj*64+tx*4+j;
      Mb[r*JD+c] = acc[i][j];
      if (ti != tj) Mb[c*JD+r] = acc[i][j];
    }
}

// ---------------------------------------------------------------------------
// K5: recon = A * M, fused depatchify. grid (128 patch-blocks, 16 batches).
// ---------------------------------------------------------------------------
__global__ __launch_bounds__(256) void k_recon(const float* __restrict__ x,
                                               const float* __restrict__ Mg,
                                               float* __restrict__ out) {
  const int nb = blockIdx.x;
  const int b  = blockIdx.y;
  const int t  = threadIdx.x;
  __shared__ float At[32][17];
  __shared__ float Mt[16][JD];
  const float* xb = x + (size_t)b*3*IMG*IMG;
  const float* Mb = Mg + (size_t)b*JD*JD;
  float* ob = out + (size_t)b*3*IMG*IMG;
  const int pg = t >> 4;
  const int jg = t & 15;
  float acc[2][12];
#pragma unroll
  for (int i=0;i<2;i++)
#pragma unroll
    for (int j=0;j<12;j++) acc[i][j]=0.f;
  for (int j0=0; j0<JD; j0+=16) {
    for (int f=t; f<512; f+=256) {
      const int nl = f >> 4, jj = f & 15;
      const int j = j0 + jj;
      const int n = nb*32 + nl;
      const int hh = n >> 6, ww = n & 63;
      const int c = j >> 6, p = (j >> 3) & 7, q = j & 7;
      At[nl][jj] = xb[(c*IMG + hh*8+p)*IMG + ww*8 + q];
    }
    for (int f=t; f<768; f+=256) {
      const int jj = f/48, cc = (f - jj*48)*4;
      *(float4*)(&Mt[jj][cc]) = *(const float4*)(Mb + (size_t)(j0+jj)*JD + cc);
    }
    __syncthreads();
#pragma unroll 4
    for (int jj=0;jj<16;jj++) {
      const float a0 = At[pg*2+0][jj];
      const float a1 = At[pg*2+1][jj];
      const float4 m0 = *(const float4*)(&Mt[jj][jg*12]);
      const float4 m1 = *(const float4*)(&Mt[jj][jg*12+4]);
      const float4 m2 = *(const float4*)(&Mt[jj][jg*12+8]);
      const float mm[12] = {m0.x,m0.y,m0.z,m0.w,m1.x,m1.y,m1.z,m1.w,
                            m2.x,m2.y,m2.z,m2.w};
#pragma unroll
      for (int j=0;j<12;j++) {
        acc[0][j] += a0*mm[j];
        acc[1][j] += a1*mm[j];
      }
    }
    __syncthreads();
  }
#pragma unroll
  for (int i=0;i<2;i++) {
    const int n = nb*32 + pg*2 + i;
    const int hh = n >> 6, ww = n & 63;
#pragma unroll
    for (int j4=0;j4<3;j4++) {
      const int jo = jg*12 + j4*4;
      const int c = jo >> 6, p = (jo >> 3) & 7, q = jo & 7;
      const float4 v = make_float4(acc[i][j4*4+0], acc[i][j4*4+1],
                                   acc[i][j4*4+2], acc[i][j4*4+3]);
      *(float4*)(ob + (size_t)(c*IMG + hh*8+p)*IMG + ww*8 + q) = v;
    }
  }
}

// ---------------------------------------------------------------------------
extern "C" void kernel_launch(void* const* d_in, const int* in_sizes, int n_in,
                              void* d_out, int out_size, void* d_ws, size_t ws_size,
                              hipStream_t stream) {
  (void)in_sizes; (void)n_in; (void)out_size; (void)ws_size;
  const float* x = (const float*)d_in[0];
  float* out = (float*)d_out;
  float* ws  = (float*)d_ws;

  float* part = ws;                    // dead after k_greduce
  float* Gs   = ws + 2359296;
  float* P0   = ws + 2949120;
  float* P1   = ws + 3538944;
  // overlays on the (dead) part region:
  float* Mg   = ws;                    // 589824
  float* Wb   = ws + 786432;           // 196608
  float* Hg   = ws + 983040;           // 66560 (64x65 per batch)
  float* v5   = ws + 1052672;          // 5120
  float* Vtg  = ws + 1057792;          // 32768
  float* Btg  = ws + 1090560;          // 98304 (32x192 per batch)

  k_gram  <<<dim3(4,4,16), 256, 0, stream>>>(x, part);
  k_greduce<<<2304,        256, 0, stream>>>(part, Gs);
  k_sq    <<<dim3(6,16),   256, 0, stream>>>(Gs, P0);   // Gs^2
  k_sq    <<<dim3(6,16),   256, 0, stream>>>(P0, P1);   // Gs^4
  k_sq    <<<dim3(6,16),   256, 0, stream>>>(P1, P0);   // Gs^8
  k_sq    <<<dim3(6,16),   256, 0, stream>>>(P0, P1);   // Gs^16
  k_sq    <<<dim3(6,16),   256, 0, stream>>>(P1, P0);   // Gs^32
  k_subH  <<<16,           256, 0, stream>>>(P0, Gs, Wb, Hg);
  k_trid  <<<16,           256, 0, stream>>>(Hg, v5);
  k_vec   <<<16,           256, 0, stream>>>(Hg, v5, Vtg);
  k_bv    <<<16,           256, 0, stream>>>(Wb, Vtg, Btg);
  k_mm    <<<dim3(6,16),   256, 0, stream>>>(Btg, Mg);
  k_recon <<<dim3(128,16), 256, 0, stream>>>(x, Mg, out);
}

// Round 7
// 927.416 us; speedup vs baseline: 1.1440x; 1.0599x over previous
//
#include <hip/hip_runtime.h>
#include <cstdint>
#include <cstddef>

#define IMG 512
#define JD 192

__device__ inline float fast_rcp(float x) { return __builtin_amdgcn_rcpf(x); }

// ---------------------------------------------------------------------------
// K1: partial Gram. grid (4 patch-chunks, 4 row-slabs, 16 batches), 256 thr.
// ---------------------------------------------------------------------------
__global__ __launch_bounds__(256) void k_gram(const float* __restrict__ x,
                                              float* __restrict__ part) {
  const int ck = blockIdx.x;
  const int sl = blockIdx.y;
  const int b  = blockIdx.z;
  const int t  = threadIdx.x;
  __shared__ float tile[32][JD];
  const int ty = t >> 5;
  const int tx = t & 31;
  const int r0 = sl*48 + ty*6;
  const int c0 = tx*6;
  float acc[6][6];
#pragma unroll
  for (int i=0;i<6;i++)
#pragma unroll
    for (int j=0;j<6;j++) acc[i][j]=0.f;
  const float* xb = x + (size_t)b*3*IMG*IMG;
  const int nbeg = ck*1024;
  for (int n0 = nbeg; n0 < nbeg+1024; n0 += 32) {
    for (int f = t; f < 32*JD; f += 256) {
      const int nl = f / JD, j = f - nl*JD;
      const int n = n0 + nl;
      const int hh = n >> 6, ww = n & 63;
      const int c = j >> 6, p = (j >> 3) & 7, q = j & 7;
      tile[nl][j] = xb[(c*IMG + hh*8+p)*IMG + ww*8 + q];
    }
    __syncthreads();
#pragma unroll 4
    for (int nl = 0; nl < 32; nl++) {
      float va[6], vb[6];
#pragma unroll
      for (int i=0;i<6;i++) va[i] = tile[nl][r0+i];
#pragma unroll
      for (int j=0;j<6;j++) vb[j] = tile[nl][c0+j];
#pragma unroll
      for (int i=0;i<6;i++)
#pragma unroll
        for (int j=0;j<6;j++) acc[i][j] += va[i]*vb[j];
    }
    __syncthreads();
  }
  float* dst = part + (((size_t)(b*4 + sl))*4 + ck) * (size_t)(48*JD);
#pragma unroll
  for (int i=0;i<6;i++)
#pragma unroll
    for (int j=0;j<6;j++)
      dst[(ty*6+i)*JD + c0+j] = acc[i][j];
}

// ---------------------------------------------------------------------------
// K2: reduce 4 chunk-partials -> Gs = G / 4096
// ---------------------------------------------------------------------------
__global__ __launch_bounds__(256) void k_greduce(const float* __restrict__ part,
                                                 float* __restrict__ Gs) {
  const int idx = blockIdx.x*256 + threadIdx.x;
  const int b = idx / (JD*JD);
  const int e = idx - b*(JD*JD);
  const int r = e / JD;
  const int sl = r / 48;
  const int w = (r - sl*48)*JD + (e - r*JD);
  const float* p = part + ((size_t)(b*4+sl))*4*(48*JD) + w;
  float s = 0.f;
#pragma unroll
  for (int ck=0; ck<4; ck++) s += p[(size_t)ck*48*JD];
  Gs[idx] = s * (1.0f/4096.0f);
}

// ---------------------------------------------------------------------------
// K3: D = S*S for symmetric S (per batch), lower-tri tile pairs.
// ---------------------------------------------------------------------------
__global__ __launch_bounds__(256) void k_sq(const float* __restrict__ S,
                                            float* __restrict__ D) {
  const int tp = blockIdx.x;
  const int b  = blockIdx.y;
  int ti, tj;
  if      (tp==0){ti=0;tj=0;} else if (tp==1){ti=1;tj=0;}
  else if (tp==2){ti=1;tj=1;} else if (tp==3){ti=2;tj=0;}
  else if (tp==4){ti=2;tj=1;} else            {ti=2;tj=2;}
  const float* Sb = S + (size_t)b*JD*JD;
  float* Db = D + (size_t)b*JD*JD;
  __shared__ float Ar[64][33];
  __shared__ float Br[64][33];
  const int t = threadIdx.x;
  const int ty = t >> 4, tx = t & 15;
  float acc[4][4];
#pragma unroll
  for (int i=0;i<4;i++)
#pragma unroll
    for (int j=0;j<4;j++) acc[i][j]=0.f;
  for (int k0=0; k0<JD; k0+=32) {
    for (int f=t; f<2048; f+=256) {
      const int row = f >> 5, kk = f & 31;
      Ar[row][kk] = Sb[(ti*64+row)*JD + k0+kk];
      Br[row][kk] = Sb[(tj*64+row)*JD + k0+kk];
    }
    __syncthreads();
#pragma unroll 4
    for (int k=0;k<32;k++) {
      float va[4], vb[4];
#pragma unroll
      for (int i=0;i<4;i++) va[i] = Ar[ty*4+i][k];
#pragma unroll
      for (int j=0;j<4;j++) vb[j] = Br[tx*4+j][k];
#pragma unroll
      for (int i=0;i<4;i++)
#pragma unroll
        for (int j=0;j<4;j++) acc[i][j] += va[i]*vb[j];
    }
    __syncthreads();
  }
#pragma unroll
  for (int i=0;i<4;i++)
#pragma unroll
    for (int j=0;j<4;j++) {
      const int r = ti*64+ty*4+i, c = tj*64+tx*4+j;
      Db[r*JD+c] = acc[i][j];
      if (ti != tj) Db[c*JD+r] = acc[i][j];
    }
}

// ---------------------------------------------------------------------------
// LDS-resident helpers for k_subH (512 threads). W: 192 rows, stride 68.
// Serial phases (Cholesky A/B, trisolve) keep their round-2 proven shapes.
// ---------------------------------------------------------------------------

// In-place ridge-CholQR of Wl (192x68 LDS). S1 is 64x68 LDS scratch. BD=512.
__device__ void orth_lds(float* __restrict__ Wl, float* __restrict__ S1,
                         float* __restrict__ rdv, float* __restrict__ pdv,
                         float* __restrict__ misc, int t, float ridge) {
  const int ty = t >> 5, tx = t & 31;   // 16x32 grid -> 4x2 outputs
  float acc[4][2];
#pragma unroll
  for (int i=0;i<4;i++)
#pragma unroll
    for (int j=0;j<2;j++) acc[i][j]=0.f;
  __syncthreads();
  // ---- Gram: S1 = W^T W (per-element sum order identical to 256-thr ver) --
#pragma unroll 2
  for (int r=0; r<JD; r++) {
    const float4 va4 = *(const float4*)(Wl + r*68 + ty*4);
    const float2 vb2 = *(const float2*)(Wl + r*68 + tx*2);
    const float a4[4] = {va4.x, va4.y, va4.z, va4.w};
    const float b2[2] = {vb2.x, vb2.y};
#pragma unroll
    for (int i=0;i<4;i++)
#pragma unroll
      for (int j=0;j<2;j++) acc[i][j] += a4[i]*b2[j];
  }
#pragma unroll
  for (int i=0;i<4;i++)
#pragma unroll
    for (int j=0;j<2;j++)
      S1[(ty*4+i)*68 + tx*2+j] = acc[i][j];
  __syncthreads();
  // ---- ridge ----
  if (ridge > 0.f) {
    if (t < 64) {
      float d = S1[t*68+t];
#pragma unroll
      for (int o=1;o<64;o<<=1) d = fmaxf(d, __shfl_xor(d, o));
      if (t == 0) misc[0] = d * ridge;
    }
    __syncthreads();
    if (t < 64) S1[t*68+t] += misc[0];
    __syncthreads();
  }
  // ---- blocked Cholesky (LDL-form, panel = 16) ----
  for (int p=0; p<4; p++) {
    const int b16 = p*16;
    // phase A: diagonal 16x16 factor, single wave, no barriers (unchanged)
    if (t < 64) {
      for (int jj=0; jj<16; jj++) {
        const int j = b16 + jj;
        const float invd = fast_rcp(S1[j*68+j]);
        if (t == 0) pdv[jj] = invd;
        const int nit = (15-jj)*16;
        for (int f=t; f<nit; f+=64) {
          const int i = j+1 + (f>>4);
          const int k = j+1 + (f&15);
          if (k <= i)
            S1[i*68+k] -= S1[i*68+j]*S1[k*68+j]*invd;
        }
      }
    }
    __syncthreads();
    // phase B: panel rows below diag block, one thread per row (unchanged)
    const int rb = b16 + 16;
    if (t < 64 - rb) {
      const int r = rb + t;
      float pr[16];
      float4* prp = (float4*)pr;
      prp[0] = *(const float4*)(S1 + r*68 + b16);
      prp[1] = *(const float4*)(S1 + r*68 + b16 + 4);
      prp[2] = *(const float4*)(S1 + r*68 + b16 + 8);
      prp[3] = *(const float4*)(S1 + r*68 + b16 + 12);
#pragma unroll
      for (int c=1; c<16; c++) {
        float s = pr[c];
#pragma unroll
        for (int j=0; j<c; j++) s -= pr[j]*S1[(b16+c)*68 + b16+j]*pdv[j];
        pr[c] = s;
      }
      *(float4*)(S1 + r*68 + b16)      = prp[0];
      *(float4*)(S1 + r*68 + b16 + 4)  = prp[1];
      *(float4*)(S1 + r*68 + b16 + 8)  = prp[2];
      *(float4*)(S1 + r*68 + b16 + 12) = prp[3];
    }
    __syncthreads();
    // phase C: trailing rank-16 update, fully parallel (stride 512)
    for (int f=t; f<2304; f+=512) {
      const int i = rb + f/48;
      const int k = rb + (f - (f/48)*48);
      if (i < 64 && k < 64 && k <= i) {
        float s = S1[i*68+k];
#pragma unroll
        for (int jj=0; jj<16; jj++)
          s -= S1[i*68 + b16+jj]*S1[k*68 + b16+jj]*pdv[jj];
        S1[i*68+k] = s;
      }
    }
    __syncthreads();
  }
  // ---- scale columns, triangular solve in registers (unchanged shape) ----
  if (t < 64) rdv[t] = rsqrtf(S1[t*68+t]);
  __syncthreads();
  for (int f=t; f<4096; f+=512) {
    const int i = f>>6, k = f&63;
    if (k < i) S1[i*68+k] *= rdv[k];
  }
  __syncthreads();
  if (t < JD) {
    float w[64];
    float4* wp = (float4*)w;
#pragma unroll
    for (int c4=0;c4<16;c4++) wp[c4] = *(const float4*)(Wl + t*68 + c4*4);
#pragma unroll
    for (int c=0;c<64;c++) {
      float v = w[c];
#pragma unroll
      for (int k=0;k<c;k++) v -= w[k]*S1[c*68+k];
      w[c] = v * rdv[c];
    }
#pragma unroll
    for (int c4=0;c4<16;c4++) *(float4*)(Wl + t*68 + c4*4) = wp[c4];
  }
  __syncthreads();
}

// Wout(192x68 LDS) = G(192x192 global) * Win(192x68 LDS); Gt scratch. BD=512.
__device__ void mm_lds(const float* __restrict__ G, const float* __restrict__ Win,
                       float* __restrict__ Wout, float* __restrict__ Gt, int t) {
  const int rg = t >> 3;   // 0..63 -> rows rg*3..+2
  const int cg = t & 7;    // cols cg*8..+7
  float acc[3][8];
#pragma unroll
  for (int i=0;i<3;i++)
#pragma unroll
    for (int j=0;j<8;j++) acc[i][j]=0.f;
  for (int k0=0; k0<JD; k0+=32) {
    __syncthreads();
    for (int f=t; f<6144; f+=512) {
      const int r = f >> 5, kk = f & 31;
      Gt[kk*193 + r] = G[r*JD + k0 + kk];
    }
    __syncthreads();
#pragma unroll 2
    for (int k=0;k<32;k++) {
      const float a0 = Gt[k*193 + rg*3+0];
      const float a1 = Gt[k*193 + rg*3+1];
      const float a2 = Gt[k*193 + rg*3+2];
      const float* wr = Win + (k0+k)*68 + cg*8;
#pragma unroll
      for (int j4=0;j4<2;j4++) {
        const float4 b4 = *(const float4*)(wr + 4*j4);
        const float bb[4] = {b4.x, b4.y, b4.z, b4.w};
#pragma unroll
        for (int jj=0;jj<4;jj++) {
          acc[0][j4*4+jj] += a0*bb[jj];
          acc[1][j4*4+jj] += a1*bb[jj];
          acc[2][j4*4+jj] += a2*bb[jj];
        }
      }
    }
  }
  __syncthreads();
#pragma unroll
  for (int i=0;i<3;i++)
#pragma unroll
    for (int j=0;j<8;j++)
      Wout[(rg*3+i)*68 + cg*8 + j] = acc[i][j];
  __syncthreads();
}

// S1 = X^T * Y (both 192x68 LDS), dst stride ss. BD=512.
__device__ void hgemm_lds(const float* __restrict__ X, const float* __restrict__ Y,
                          float* __restrict__ S1, int ss, int t) {
  const int ty = t >> 5, tx = t & 31;
  float acc[4][2];
#pragma unroll
  for (int i=0;i<4;i++)
#pragma unroll
    for (int j=0;j<2;j++) acc[i][j]=0.f;
#pragma unroll 2
  for (int r=0; r<JD; r++) {
    const float4 va4 = *(const float4*)(X + r*68 + ty*4);
    const float2 vb2 = *(const float2*)(Y + r*68 + tx*2);
    const float a4[4] = {va4.x, va4.y, va4.z, va4.w};
    const float b2[2] = {vb2.x, vb2.y};
#pragma unroll
    for (int i=0;i<4;i++)
#pragma unroll
      for (int j=0;j<2;j++) acc[i][j] += a4[i]*b2[j];
  }
  __syncthreads();
#pragma unroll
  for (int i=0;i<4;i++)
#pragma unroll
    for (int j=0;j<2;j++)
      S1[(ty*4+i)*ss + tx*2+j] = acc[i][j];
  __syncthreads();
}

// ---------------------------------------------------------------------------
// K4a: subspace basis + H, all W traffic in LDS. grid 16, 512 thr.
// Outputs: WbG (192x64 row-major), Hgg (64x65-strided).
// ---------------------------------------------------------------------------
__global__ __launch_bounds__(512) void k_subH(const float* __restrict__ G32g,
                                              const float* __restrict__ Gsg,
                                              float* __restrict__ WbG,
                                              float* __restrict__ Hgg) {
  const int b = blockIdx.x;
  const int t = threadIdx.x;
  __shared__ float W0l[192*68];
  __shared__ float W1l[192*68];
  __shared__ float scr[32*193];   // unions: S1 (64x68) / Gt (32x193) / H (64x65)
  __shared__ float rdv[64];
  __shared__ float pdv[16];
  __shared__ float misc[8];
  const float* Gb  = G32g + (size_t)b*JD*JD;
  const float* Gsb = Gsg  + (size_t)b*JD*JD;

  for (int f=t; f<JD*64; f+=512)
    W0l[(f>>6)*68 + (f&63)] = Gb[(f>>6)*JD + (f&63)];
  __syncthreads();

  orth_lds(W0l, scr, rdv, pdv, misc, t, 1e-6f);   // span-preserving (ridged)
  mm_lds(Gb, W0l, W1l, scr, t);                   // power +32
  orth_lds(W1l, scr, rdv, pdv, misc, t, 1e-6f);
  orth_lds(W1l, scr, rdv, pdv, misc, t, 0.f);     // CholQR2 clean pass

  // H = W^T Gs W  (T1 = Gs*W into W0l, then hgemm -> scr at stride 65)
  mm_lds(Gsb, W1l, W0l, scr, t);
  hgemm_lds(W1l, W0l, scr, 65, t);

  float* Wb = WbG + (size_t)b*JD*64;
  for (int f=t; f<JD*64; f+=512)
    Wb[f] = W1l[(f>>6)*68 + (f&63)];
  float* Hb = Hgg + (size_t)b*4160;
  for (int f=t; f<4160; f+=512) Hb[f] = scr[f];
}

// ---------------------------------------------------------------------------
// Householder tridiag of A (64x64, stride 65) in place (256-thread update).
// ---------------------------------------------------------------------------
__device__ void dev_tridiag(float* __restrict__ A, float* a, float* b2,
                            float* bsg, float* v0s, float* bts,
                            float* vvec, float* wvec, int t) {
  for (int j=0; j<=61; j++) {
    const int m = 63 - j;
    if (t < 64) {
      float xi = (t < m) ? A[j*65 + (j+1+t)] : 0.f;
      float nr = xi*xi;
#pragma unroll
      for (int o=1;o<64;o<<=1) nr += __shfl_xor(nr, o);
      const float sig = sqrtf(nr);
      const float alpha = __shfl(xi, 0);
      const float sgn = (alpha >= 0.f) ? 1.f : -1.f;
      const float v0 = alpha + sgn*sig;
      const float beta = (sig > 1e-20f) ? 1.0f/(sig*fabsf(v0)) : 0.f;
      if (t < m) vvec[t] = (t==0) ? v0 : xi;
      if (t == 0) {
        a[j] = A[j*65+j]; b2[j] = nr; bsg[j] = -sgn*sig;
        v0s[j] = v0; bts[j] = beta;
      }
      float pv = 0.f;
      if (t < m) {
        const float* row = A + (j+1+t)*65 + (j+1);
        for (int c=0;c<m;c++) pv += row[c]*vvec[c];
        pv *= beta;
      }
      float dp = (t<m) ? vvec[t]*pv : 0.f;
#pragma unroll
      for (int o=1;o<64;o<<=1) dp += __shfl_xor(dp, o);
      const float gamma = 0.5f*beta*dp;
      if (t < m) wvec[t] = pv - gamma*vvec[t];
    }
    __syncthreads();
    const int mm = m*m;
    for (int f=t; f<mm; f+=256) {
      const int r = f/m, c = f - r*m;
      A[(j+1+r)*65 + (j+1+c)] -= vvec[r]*wvec[c] + wvec[r]*vvec[c];
    }
    __syncthreads();
  }
  if (t == 0) {
    a[62] = A[62*65+62];
    a[63] = A[63*65+63];
    const float bb = A[62*65+63];
    b2[62] = bb*bb;
    bsg[62] = bb;
  }
  __syncthreads();
}

// ---------------------------------------------------------------------------
// K4b: tridiagonalize H. grid 16. Exports reflectors (in Hgg) + vec5.
// ---------------------------------------------------------------------------
__global__ __launch_bounds__(256) void k_trid(float* __restrict__ Hgg,
                                              float* __restrict__ vec5) {
  const int b = blockIdx.x;
  const int t = threadIdx.x;
  __shared__ float SH[4160];
  __shared__ float a64[64];
  __shared__ float b2v[64];
  __shared__ float bsg[64];
  __shared__ float v0s[64];
  __shared__ float bts[64];
  __shared__ float vvec[64];
  __shared__ float wvec[64];
  float* Hb = Hgg + (size_t)b*4160;
  for (int f=t; f<4160; f+=256) SH[f] = Hb[f];
  __syncthreads();
  dev_tridiag(SH, a64, b2v, bsg, v0s, bts, vvec, wvec, t);
  for (int f=t; f<4160; f+=256) Hb[f] = SH[f];   // reflectors back out
  float* vb = vec5 + (size_t)b*320;
  if (t < 64) {
    vb[t]     = a64[t];
    vb[64+t]  = b2v[t];
    vb[128+t] = bsg[t];
    vb[192+t] = v0s[t];
    vb[256+t] = bts[t];
  }
}

// Sturm count with fast reciprocal
__device__ inline int sturm_cnt_fast(const float* a, const float* b2, float sig) {
  float d = a[0] - sig;
  int n = (d < 0.f) ? 1 : 0;
#pragma unroll 8
  for (int i=1;i<64;i++) {
    const float dd = (fabsf(d) < 1e-20f) ? -1e-20f : d;
    d = (a[i]-sig) - b2[i-1]*fast_rcp(dd);
    n += (d < 0.f) ? 1 : 0;
  }
  return n;
}

__device__ inline float dguard(float d) {
  if (fabsf(d) < 1e-12f) return (d < 0.f) ? -1e-12f : 1e-12f;
  return d;
}

// ---------------------------------------------------------------------------
// K4c: eigenvalues (9-section Sturm) + twisted inverse iteration + CholQR32 +
// Householder backtransform. grid 16. Output Vt (64x32) -> VtG.
// ---------------------------------------------------------------------------
__global__ __launch_bounds__(256) void k_vec(const float* __restrict__ Hgg,
                                             const float* __restrict__ vec5,
                                             float* __restrict__ VtG) {
  const int b = blockIdx.x;
  const int t = threadIdx.x;
  __shared__ float SH[4160];
  __shared__ float Vt[64*36];
  __shared__ float dpA[64*33];
  __shared__ float dmA[64*33];
  __shared__ float ps[8*33];
  __shared__ float wvred[32];
  __shared__ float rdv[64];
  __shared__ float a64[64];
  __shared__ float b2v[64];
  __shared__ float bsg[64];
  __shared__ float v0s[64];
  __shared__ float bts[64];
  __shared__ float lam[32];
  __shared__ float misc[8];
  const float* Hb = Hgg + (size_t)b*4160;
  const float* vb = vec5 + (size_t)b*320;
  for (int f=t; f<4160; f+=256) SH[f] = Hb[f];   // issue early, used late
  if (t < 64) {
    a64[t] = vb[t];
    b2v[t] = vb[64+t];
    bsg[t] = vb[128+t];
    v0s[t] = vb[192+t];
    bts[t] = vb[256+t];
  }
  __syncthreads();

  // ---- spectrum bounds (Gershgorin) ----
  if (t < 64) {
    const float bl = (t>0)  ? sqrtf(b2v[t-1]) : 0.f;
    const float br = (t<63) ? sqrtf(b2v[t])   : 0.f;
    float lo = a64[t] - bl - br, hi = a64[t] + bl + br;
#pragma unroll
    for (int o=1;o<64;o<<=1) {
      lo = fminf(lo, __shfl_xor(lo,o));
      hi = fmaxf(hi, __shfl_xor(hi,o));
    }
    if (t == 0) { misc[0] = lo - 1e-4f; misc[1] = hi + 1e-4f; }
  }
  __syncthreads();

  // ---- 9-section search: 8 probes/eig in parallel, 10 rounds ----
  {
    const int l = t >> 3, g = t & 7;
    const int r = 32 + l;
    float L = misc[0], H = misc[1];
    for (int it=0; it<10; it++) {
      const float mid = L + (H-L)*((float)(g+1)*(1.0f/9.0f));
      const int cnt = sturm_cnt_fast(a64, b2v, mid);
      float nL = L, nH = H;
#pragma unroll
      for (int k=0;k<8;k++) {
        const int ck = __shfl(cnt, k, 8);
        const float pk = L + (H-L)*((float)(k+1)*(1.0f/9.0f));
        if (ck <= r) nL = fmaxf(nL, pk); else nH = fminf(nH, pk);
      }
      L = nL; H = nH;
    }
    if (g == 0) lam[l] = 0.5f*(L+H);
  }
  __syncthreads();

  // ---- twisted-factorization inverse iteration (lane l = one eigvec) ----
  if (t < 32) {
    const int l = t;
    const float lm = lam[l];
    float d = dguard(a64[0] - lm);
    dpA[0*33+l] = d;
    for (int i=1;i<64;i++) {
      d = dguard((a64[i]-lm) - b2v[i-1]*fast_rcp(d));
      dpA[i*33+l] = d;
    }
    float e = dguard(a64[63] - lm);
    dmA[63*33+l] = e;
    for (int i=62;i>=0;i--) {
      e = dguard((a64[i]-lm) - b2v[i]*fast_rcp(e));
      dmA[i*33+l] = e;
    }
    int ks = 0; float gbest = 1e30f;
    for (int i=0;i<64;i++) {
      const float g = fabsf(dpA[i*33+l] + dmA[i*33+l] - (a64[i]-lm));
      if (g < gbest) { gbest = g; ks = i; }
    }
    Vt[ks*36+l] = 1.f;
    float z = 1.f;
    for (int i=ks-1;i>=0;i--) {
      z = -(bsg[i]*z) * fast_rcp(dpA[i*33+l]);
      z = fminf(fmaxf(z, -1e18f), 1e18f);
      Vt[i*36+l] = z;
    }
    z = 1.f;
    for (int i=ks+1;i<64;i++) {
      z = -(bsg[i-1]*z) * fast_rcp(dmA[i*33+l]);
      z = fminf(fmaxf(z, -1e18f), 1e18f);
      Vt[i*36+l] = z;
    }
    float nr2 = 0.f;
    for (int i=0;i<64;i++) { const float zz = Vt[i*36+l]; nr2 += zz*zz; }
    const float inv = rsqrtf(nr2);
    for (int i=0;i<64;i++) Vt[i*36+l] *= inv;
  }
  __syncthreads();

  // ---- CholQR-32 safety pass on Vt ----
  for (int f=t; f<1024; f+=256) {
    const int i = f>>5, j = f&31;
    float s = 0.f;
    for (int r=0;r<64;r++) s += Vt[r*36+i]*Vt[r*36+j];
    dpA[i*33+j] = s;
  }
  __syncthreads();
  if (t == 0) {
    float m = 0.f;
    for (int j=0;j<32;j++) m = fmaxf(m, dpA[j*33+j]);
    misc[2] = m * 1e-7f;
  }
  __syncthreads();
  if (t < 32) dpA[t*33+t] += misc[2];
  for (int j=0;j<31;j++) {
    __syncthreads();
    const float invd = fast_rcp(dpA[j*33+j]);
    for (int f=t; f<(31-j)*32; f+=256) {
      const int i = j+1 + (f>>5);
      const int k = f & 31;
      if (k > j && k <= i)
        dpA[i*33+k] -= dpA[i*33+j]*dpA[k*33+j]*invd;
    }
  }
  __syncthreads();
  if (t < 32) rdv[t] = rsqrtf(dpA[t*33+t]);
  __syncthreads();
  for (int f=t; f<1024; f+=256) {
    const int i = f>>5, k = f&31;
    if (k < i) dpA[i*33+k] *= rdv[k];
  }
  __syncthreads();
  if (t < 64) {
    float w[32];
#pragma unroll
    for (int c=0;c<32;c++) w[c] = Vt[t*36+c];
#pragma unroll
    for (int c=0;c<32;c++) {
      float v = w[c];
#pragma unroll
      for (int k=0;k<c;k++) v -= w[k]*dpA[c*33+k];
      w[c] = v * rdv[c];
    }
#pragma unroll
    for (int c=0;c<32;c++) Vt[t*36+c] = w[c];
  }
  __syncthreads();

  // ---- backtransform: V = H_0 H_1 ... H_61 Vt ----
  for (int j=61; j>=0; j--) {
    const int m = 63 - j;
    {
      const int c = t & 31, g = t >> 5;
      float s = 0.f;
      for (int r=g; r<m; r+=8) {
        const float vr = (r==0) ? v0s[j] : SH[j*65 + (j+1+r)];
        s += vr * Vt[(j+1+r)*36 + c];
      }
      ps[g*33+c] = s;
    }
    __syncthreads();
    if (t < 32) {
      float s = 0.f;
#pragma unroll
      for (int g=0;g<8;g++) s += ps[g*33+t];
      wvred[t] = s * bts[j];
    }
    __syncthreads();
    {
      const int c = t & 31, g = t >> 5;
      for (int r=g; r<m; r+=8) {
        const float vr = (r==0) ? v0s[j] : SH[j*65 + (j+1+r)];
        Vt[(j+1+r)*36 + c] -= vr * wvred[c];
      }
    }
    __syncthreads();
  }

  float* Vb = VtG + (size_t)b*2048;
  for (int f=t; f<2048; f+=256) Vb[f] = Vt[(f>>5)*36 + (f&31)];
}

// ---------------------------------------------------------------------------
// K4d: B^T = (W*V)^T -> Btg (32 x 192 row-major per batch). grid 16.
// ---------------------------------------------------------------------------
__global__ __launch_bounds__(256) void k_bv(const float* __restrict__ WbG,
                                            const float* __restrict__ VtG,
                                            float* __restrict__ Btg) {
  const int b = blockIdx.x;
  const int t = threadIdx.x;
  __shared__ float Vt[64*36];
  const float* W = WbG + (size_t)b*JD*64;
  const float* Vb = VtG + (size_t)b*2048;
  float* Bt = Btg + (size_t)b*32*JD;
  for (int f=t; f<2048; f+=256) Vt[(f>>5)*36 + (f&31)] = Vb[f];
  __syncthreads();
  if (t < JD) {
    float accv[32];
#pragma unroll
    for (int c=0;c<32;c++) accv[c] = 0.f;
    const float4* crow = (const float4*)(W + t*64);
#pragma unroll 2
    for (int kb=0; kb<16; kb++) {
      const float4 av = crow[kb];
      const float a4[4] = {av.x, av.y, av.z, av.w};
#pragma unroll
      for (int ki=0; ki<4; ki++) {
        const float aa = a4[ki];
        const float* vrow = Vt + (kb*4+ki)*36;
        const float4 v0 = *(const float4*)(vrow+0);
        const float4 v1 = *(const float4*)(vrow+4);
        const float4 v2 = *(const float4*)(vrow+8);
        const float4 v3 = *(const float4*)(vrow+12);
        const float4 v4 = *(const float4*)(vrow+16);
        const float4 v5 = *(const float4*)(vrow+20);
        const float4 v6 = *(const float4*)(vrow+24);
        const float4 v7 = *(const float4*)(vrow+28);
        accv[0]+=aa*v0.x; accv[1]+=aa*v0.y; accv[2]+=aa*v0.z; accv[3]+=aa*v0.w;
        accv[4]+=aa*v1.x; accv[5]+=aa*v1.y; accv[6]+=aa*v1.z; accv[7]+=aa*v1.w;
        accv[8]+=aa*v2.x; accv[9]+=aa*v2.y; accv[10]+=aa*v2.z; accv[11]+=aa*v2.w;
        accv[12]+=aa*v3.x; accv[13]+=aa*v3.y; accv[14]+=aa*v3.z; accv[15]+=aa*v3.w;
        accv[16]+=aa*v4.x; accv[17]+=aa*v4.y; accv[18]+=aa*v4.z; accv[19]+=aa*v4.w;
        accv[20]+=aa*v5.x; accv[21]+=aa*v5.y; accv[22]+=aa*v5.z; accv[23]+=aa*v5.w;
        accv[24]+=aa*v6.x; accv[25]+=aa*v6.y; accv[26]+=aa*v6.z; accv[27]+=aa*v6.w;
        accv[28]+=aa*v7.x; accv[29]+=aa*v7.y; accv[30]+=aa*v7.z; accv[31]+=aa*v7.w;
      }
    }
#pragma unroll
    for (int c=0;c<32;c++) Bt[c*JD + t] = accv[c];
  }
}

// ---------------------------------------------------------------------------
// K4e: M = B B^T = Bt^T Bt, lower-tri tile pairs (like k_sq). grid (6,16).
// ---------------------------------------------------------------------------
__global__ __launch_bounds__(256) void k_mm(const float* __restrict__ Btg,
                                            float* __restrict__ Mg) {
  const int tp = blockIdx.x;
  const int b  = blockIdx.y;
  int ti, tj;
  if      (tp==0){ti=0;tj=0;} else if (tp==1){ti=1;tj=0;}
  else if (tp==2){ti=1;tj=1;} else if (tp==3){ti=2;tj=0;}
  else if (tp==4){ti=2;tj=1;} else            {ti=2;tj=2;}
  const float* Bt = Btg + (size_t)b*32*JD;
  float* Mb = Mg + (size_t)b*JD*JD;
  __shared__ float Ar[32][68];
  __shared__ float Br[32][68];
  const int t = threadIdx.x;
  const int ty = t >> 4, tx = t & 15;
  for (int f=t; f<2048; f+=256) {
    const int k = f >> 6, c = f & 63;
    Ar[k][c] = Bt[k*JD + ti*64 + c];
    Br[k][c] = Bt[k*JD + tj*64 + c];
  }
  __syncthreads();
  float acc[4][4];
#pragma unroll
  for (int i=0;i<4;i++)
#pragma unroll
    for (int j=0;j<4;j++) acc[i][j]=0.f;
#pragma unroll 4
  for (int k=0;k<32;k++) {
    const float4 va4 = *(const float4*)(&Ar[k][ty*4]);
    const float4 vb4 = *(const float4*)(&Br[k][tx*4]);
    const float a4[4] = {va4.x, va4.y, va4.z, va4.w};
    const float b4[4] = {vb4.x, vb4.y, vb4.z, vb4.w};
#pragma unroll
    for (int i=0;i<4;i++)
#pragma unroll
      for (int j=0;j<4;j++) acc[i][j] += a4[i]*b4[j];
  }
#pragma unroll
  for (int i=0;i<4;i++)
#pragma unroll
    for (int j=0;j<4;j++) {
      const int r = ti*64+ty*4+i, c = tj*64+tx*4+j;
      Mb[r*JD+c] = acc[i][j];
      if (ti != tj) Mb[c*JD+r] = acc[i][j];
    }
}

// ---------------------------------------------------------------------------
// K5: recon = A * M, fused depatchify. grid (128 patch-blocks, 16 batches).
// ---------------------------------------------------------------------------
__global__ __launch_bounds__(256) void k_recon(const float* __restrict__ x,
                                               const float* __restrict__ Mg,
                                               float* __restrict__ out) {
  const int nb = blockIdx.x;
  const int b  = blockIdx.y;
  const int t  = threadIdx.x;
  __shared__ float At[32][17];
  __shared__ float Mt[16][JD];
  const float* xb = x + (size_t)b*3*IMG*IMG;
  const float* Mb = Mg + (size_t)b*JD*JD;
  float* ob = out + (size_t)b*3*IMG*IMG;
  const int pg = t >> 4;
  const int jg = t & 15;
  float acc[2][12];
#pragma unroll
  for (int i=0;i<2;i++)
#pragma unroll
    for (int j=0;j<12;j++) acc[i][j]=0.f;
  for (int j0=0; j0<JD; j0+=16) {
    for (int f=t; f<512; f+=256) {
      const int nl = f >> 4, jj = f & 15;
      const int j = j0 + jj;
      const int n = nb*32 + nl;
      const int hh = n >> 6, ww = n & 63;
      const int c = j >> 6, p = (j >> 3) & 7, q = j & 7;
      At[nl][jj] = xb[(c*IMG + hh*8+p)*IMG + ww*8 + q];
    }
    for (int f=t; f<768; f+=256) {
      const int jj = f/48, cc = (f - jj*48)*4;
      *(float4*)(&Mt[jj][cc]) = *(const float4*)(Mb + (size_t)(j0+jj)*JD + cc);
    }
    __syncthreads();
#pragma unroll 4
    for (int jj=0;jj<16;jj++) {
      const float a0 = At[pg*2+0][jj];
      const float a1 = At[pg*2+1][jj];
      const float4 m0 = *(const float4*)(&Mt[jj][jg*12]);
      const float4 m1 = *(const float4*)(&Mt[jj][jg*12+4]);
      const float4 m2 = *(const float4*)(&Mt[jj][jg*12+8]);
      const float mm[12] = {m0.x,m0.y,m0.z,m0.w,m1.x,m1.y,m1.z,m1.w,
                            m2.x,m2.y,m2.z,m2.w};
#pragma unroll
      for (int j=0;j<12;j++) {
        acc[0][j] += a0*mm[j];
        acc[1][j] += a1*mm[j];
      }
    }
    __syncthreads();
  }
#pragma unroll
  for (int i=0;i<2;i++) {
    const int n = nb*32 + pg*2 + i;
    const int hh = n >> 6, ww = n & 63;
#pragma unroll
    for (int j4=0;j4<3;j4++) {
      const int jo = jg*12 + j4*4;
      const int c = jo >> 6, p = (jo >> 3) & 7, q = jo & 7;
      const float4 v = make_float4(acc[i][j4*4+0], acc[i][j4*4+1],
                                   acc[i][j4*4+2], acc[i][j4*4+3]);
      *(float4*)(ob + (size_t)(c*IMG + hh*8+p)*IMG + ww*8 + q) = v;
    }
  }
}

// ---------------------------------------------------------------------------
extern "C" void kernel_launch(void* const* d_in, const int* in_sizes, int n_in,
                              void* d_out, int out_size, void* d_ws, size_t ws_size,
                              hipStream_t stream) {
  (void)in_sizes; (void)n_in; (void)out_size; (void)ws_size;
  const float* x = (const float*)d_in[0];
  float* out = (float*)d_out;
  float* ws  = (float*)d_ws;

  float* part = ws;                    // dead after k_greduce
  float* Gs   = ws + 2359296;
  float* P0   = ws + 2949120;
  float* P1   = ws + 3538944;
  // overlays on the (dead) part region:
  float* Mg   = ws;                    // 589824
  float* Wb   = ws + 786432;           // 196608
  float* Hg   = ws + 983040;           // 66560 (64x65 per batch)
  float* v5   = ws + 1052672;          // 5120
  float* Vtg  = ws + 1057792;          // 32768
  float* Btg  = ws + 1090560;          // 98304 (32x192 per batch)

  k_gram  <<<dim3(4,4,16), 256, 0, stream>>>(x, part);
  k_greduce<<<2304,        256, 0, stream>>>(part, Gs);
  k_sq    <<<dim3(6,16),   256, 0, stream>>>(Gs, P0);   // Gs^2
  k_sq    <<<dim3(6,16),   256, 0, stream>>>(P0, P1);   // Gs^4
  k_sq    <<<dim3(6,16),   256, 0, stream>>>(P1, P0);   // Gs^8
  k_sq    <<<dim3(6,16),   256, 0, stream>>>(P0, P1);   // Gs^16
  k_sq    <<<dim3(6,16),   256, 0, stream>>>(P1, P0);   // Gs^32
  k_subH  <<<16,           512, 0, stream>>>(P0, Gs, Wb, Hg);
  k_trid  <<<16,           256, 0, stream>>>(Hg, v5);
  k_vec   <<<16,           256, 0, stream>>>(Hg, v5, Vtg);
  k_bv    <<<16,           256, 0, stream>>>(Wb, Vtg, Btg);
  k_mm    <<<dim3(6,16),   256, 0, stream>>>(Btg, Mg);
  k_recon <<<dim3(128,16), 256, 0, stream>>>(x, Mg, out);
}